// Round 3
// baseline (1474.136 us; speedup 1.0000x reference)
//
#include <hip/hip_runtime.h>

#define EPS 1e-5f

typedef __attribute__((ext_vector_type(8))) short short8;
typedef __attribute__((ext_vector_type(4))) float floatx4;
typedef __attribute__((ext_vector_type(2))) float floatx2;
typedef __attribute__((ext_vector_type(4))) unsigned short ushortx4;
typedef __attribute__((ext_vector_type(2))) unsigned short ushortx2;
typedef unsigned long long u64;

__device__ __forceinline__ unsigned short f2bf(float f) {
    unsigned u = __float_as_uint(f);
    unsigned r = (u + 0x7FFFu + ((u >> 16) & 1u)) >> 16;
    return (unsigned short)r;
}
__device__ __forceinline__ float bf2f(unsigned short h) {
    return __uint_as_float((unsigned)h << 16);
}

// ---------------------------------------------------------------- utilities
// zero per-row counts + stat accumulators (both re-derived every call)
__global__ void zero_kernel(int* __restrict__ counts, float* __restrict__ stats,
                            int n_counts, int n_stats) {
    int i = blockIdx.x * 256 + threadIdx.x;
    if (i < n_counts) counts[i] = 0;
    if (i < n_stats)  stats[i] = 0.0f;
}

// per-row degree count (400KB counter array, L2-resident)
__global__ __launch_bounds__(256) void count_kernel(const int* __restrict__ erow,
                                                    int* __restrict__ counts, int E) {
    int stride = gridDim.x * 256;
    for (int j = blockIdx.x * 256 + threadIdx.x; j < E; j += stride)
        atomicAdd(&counts[__builtin_nontemporal_load(&erow[j])], 1);
}

// single-block exclusive scan over counts[n] -> row_start[n+1].
// Also emits bucket append-cursors at 128-row boundaries (one per 64B line):
// bucket_cursor[b*16] = row_start[b*128].  Single source of truth: row_start.
__global__ __launch_bounds__(1024) void row_scan_kernel(const int* __restrict__ counts,
                                                        int* __restrict__ row_start,
                                                        int* __restrict__ bucket_cursor,
                                                        int n, int E) {
    __shared__ int lds[1024];
    int t = threadIdx.x;
    int per = (n + 1023) >> 10;
    int s0 = t * per, s1 = min(s0 + per, n);
    int sum = 0;
    for (int i = s0; i < s1; i++) sum += counts[i];
    lds[t] = sum;
    __syncthreads();
    for (int off = 1; off < 1024; off <<= 1) {
        int v = (t >= off) ? lds[t - off] : 0;
        __syncthreads();
        lds[t] += v;
        __syncthreads();
    }
    int run = lds[t] - sum;  // exclusive prefix of this thread's strip
    for (int i = s0; i < s1; i++) {
        row_start[i] = run;
        if ((i & 127) == 0) bucket_cursor[(i >> 7) * 16] = run;
        run += counts[i];
    }
    if (t == 0) row_start[n] = E;
}

// pass 1: append edges into their bucket's region of the staging array.
// Appends to a bucket are temporally dense -> ~1x write amplification.
// key packs localrow (7b) above col (17b). nt stores keep tmp out of L3.
__global__ __launch_bounds__(256) void bucket_scatter_kernel(const int* __restrict__ erow,
                                                             const int* __restrict__ ecol,
                                                             const float* __restrict__ ev,
                                                             int* __restrict__ bucket_cursor,
                                                             int2* __restrict__ tmp, int E) {
    int stride = gridDim.x * 256;
    for (int j = blockIdx.x * 256 + threadIdx.x; j < E; j += stride) {
        int r = __builtin_nontemporal_load(&erow[j]);
        int c = __builtin_nontemporal_load(&ecol[j]);
        float v = __builtin_nontemporal_load(&ev[j]);
        int b = r >> 7, lr = r & 127;
        int p = atomicAdd(&bucket_cursor[b * 16], 1);
        u64 raw = (u64)(unsigned)(c | (lr << 17)) | ((u64)__float_as_uint(v) << 32);
        __builtin_nontemporal_store(raw, (u64*)&tmp[p]);
    }
}

// pass 2: one block per bucket. Exact CSR placement using LDS cursors
// initialized directly from row_start. edges stored NORMALLY (re-read twice
// by agg1/agg2 -> want L3 residency); tmp read nt (stream-once).
__global__ __launch_bounds__(256) void place_kernel(const int2* __restrict__ tmp,
                                                    const int* __restrict__ row_start,
                                                    int2* __restrict__ edges,
                                                    int n, int E) {
    __shared__ int cur[128];
    int b = blockIdx.x, t = threadIdx.x;
    int rbase = b << 7;
    int rend  = min(rbase + 128, n);
    int bstart = row_start[rbase];
    int bend   = row_start[rend];
    if (t < 128) {
        int r = rbase + t;
        cur[t] = (r < n) ? row_start[r] : E;   // rows past n never referenced
    }
    __syncthreads();
    for (int j = bstart + t; j < bend; j += 256) {
        u64 raw = __builtin_nontemporal_load((const u64*)&tmp[j]);
        unsigned key = (unsigned)(raw & 0xFFFFFFFFu);
        int lr = key >> 17;
        int pos = atomicAdd(&cur[lr], 1);
        edges[pos] = make_int2((int)(key & 0x1FFFF), (int)(raw >> 32));
    }
}

// ---------------------------------------------------------------- W1 -> split bf16 transposed [256][512]
__global__ void prep_w1_kernel(const float* __restrict__ W1,
                               unsigned short* __restrict__ Bhi,
                               unsigned short* __restrict__ Blo) {
    int idx = blockIdx.x * 256 + threadIdx.x;   // 131072 total
    int nn = idx >> 9, k = idx & 511;
    float w = W1[(size_t)k * 256 + nn];
    unsigned short hi = f2bf(w);
    float rem = w - bf2f(hi);
    Bhi[idx] = hi;
    Blo[idx] = f2bf(rem);
}

// ---------------------------------------------------------------- GEMM1 (split-bf16 MFMA, ~fp32 exact):
// h0[M,256](bf16) = A[M,512](fp32) @ W1.  acc += ah*bh + al*bh + ah*bl.
__global__ __launch_bounds__(256) void gemm1_mfma_kernel(const float* __restrict__ A,
                                                         const unsigned short* __restrict__ Bhi,
                                                         const unsigned short* __restrict__ Blo,
                                                         unsigned short* __restrict__ H0, int M) {
    __shared__ unsigned short AsH[128][32];
    __shared__ unsigned short AsL[128][32];
    __shared__ unsigned short BsH[128][32];
    __shared__ unsigned short BsL[128][32];
    int tid  = threadIdx.x;
    int lane = tid & 63, w = tid >> 6;
    int wm = w & 1, wn = w >> 1;
    int rowBase = blockIdx.y * 128;
    int colBase = blockIdx.x * 128;

    floatx4 acc[4][4];
#pragma unroll
    for (int i = 0; i < 4; i++)
#pragma unroll
        for (int j = 0; j < 4; j++)
#pragma unroll
            for (int r = 0; r < 4; r++) acc[i][j][r] = 0.0f;

    int r    = tid >> 1;
    int half = tid & 1;
    bool aval = (rowBase + r) < M;
    const float* aptr = A + (size_t)(rowBase + r) * 512 + half * 16;
    const unsigned short* bhptr = Bhi + (size_t)(colBase + r) * 512 + half * 16;
    const unsigned short* blptr = Blo + (size_t)(colBase + r) * 512 + half * 16;

    int cl = lane & 15, quad = lane >> 4;
    int q8 = quad * 8;

    for (int k0 = 0; k0 < 512; k0 += 32) {
        float f[16];
        if (aval) {
            *(float4*)&f[0]  = *(const float4*)(aptr + k0);
            *(float4*)&f[4]  = *(const float4*)(aptr + k0 + 4);
            *(float4*)&f[8]  = *(const float4*)(aptr + k0 + 8);
            *(float4*)&f[12] = *(const float4*)(aptr + k0 + 12);
        } else {
#pragma unroll
            for (int t = 0; t < 16; t++) f[t] = 0.0f;
        }
        union { unsigned short s[16]; uint4 q[2]; } ph, pl;
#pragma unroll
        for (int t = 0; t < 16; t++) {
            unsigned short hi = f2bf(f[t]);
            ph.s[t] = hi;
            pl.s[t] = f2bf(f[t] - bf2f(hi));
        }
        *(uint4*)&AsH[r][half * 16]     = ph.q[0];
        *(uint4*)&AsH[r][half * 16 + 8] = ph.q[1];
        *(uint4*)&AsL[r][half * 16]     = pl.q[0];
        *(uint4*)&AsL[r][half * 16 + 8] = pl.q[1];
        *(uint4*)&BsH[r][half * 16]     = *(const uint4*)(bhptr + k0);
        *(uint4*)&BsH[r][half * 16 + 8] = *(const uint4*)(bhptr + k0 + 8);
        *(uint4*)&BsL[r][half * 16]     = *(const uint4*)(blptr + k0);
        *(uint4*)&BsL[r][half * 16 + 8] = *(const uint4*)(blptr + k0 + 8);
        __syncthreads();

        short8 ah[4], al[4], bh[4], bl[4];
#pragma unroll
        for (int mt = 0; mt < 4; mt++) {
            ah[mt] = *(short8*)&AsH[wm * 64 + mt * 16 + cl][q8];
            al[mt] = *(short8*)&AsL[wm * 64 + mt * 16 + cl][q8];
        }
#pragma unroll
        for (int nt = 0; nt < 4; nt++) {
            bh[nt] = *(short8*)&BsH[wn * 64 + nt * 16 + cl][q8];
            bl[nt] = *(short8*)&BsL[wn * 64 + nt * 16 + cl][q8];
        }
#pragma unroll
        for (int mt = 0; mt < 4; mt++)
#pragma unroll
            for (int nt = 0; nt < 4; nt++) {
                acc[mt][nt] = __builtin_amdgcn_mfma_f32_16x16x32_bf16(ah[mt], bh[nt], acc[mt][nt], 0, 0, 0);
                acc[mt][nt] = __builtin_amdgcn_mfma_f32_16x16x32_bf16(al[mt], bh[nt], acc[mt][nt], 0, 0, 0);
                acc[mt][nt] = __builtin_amdgcn_mfma_f32_16x16x32_bf16(ah[mt], bl[nt], acc[mt][nt], 0, 0, 0);
            }
        __syncthreads();
    }

#pragma unroll
    for (int mt = 0; mt < 4; mt++) {
#pragma unroll
        for (int reg = 0; reg < 4; reg++) {
            int gr = rowBase + wm * 64 + mt * 16 + quad * 4 + reg;
            if (gr < M) {
#pragma unroll
                for (int nt = 0; nt < 4; nt++) {
                    H0[(size_t)gr * 256 + colBase + wn * 64 + nt * 16 + cl] = f2bf(acc[mt][nt][reg]);
                }
            }
        }
    }
}

// ---------------------------------------------------------------- SpMM1 (F=256): wave per row, bf16 gather.
// Edge batch is software-pipelined (next batch loads overlap current gathers);
// edges read nt (stream-once), H1 written nt (stream-once) -> H0 stays L3-hot.
__global__ __launch_bounds__(256) void agg1_kernel(const unsigned short* __restrict__ H0,
                                                   const int* __restrict__ rs,
                                                   const int2* __restrict__ edges,
                                                   float* __restrict__ H1, int n) {
    int w = threadIdx.x >> 6, lane = threadIdx.x & 63;
    int i = blockIdx.x * 4 + w;
    if (i >= n) return;
    int start = rs[i], end = rs[i + 1];
    int fo = lane << 2;
    float accx = 0.f, accy = 0.f, accz = 0.f, accw = 0.f;
    int j = start;
    u64 e[8];
    bool have = (j + 8 <= end);
    if (have) {
#pragma unroll
        for (int t = 0; t < 8; t++) e[t] = __builtin_nontemporal_load((const u64*)&edges[j + t]);
    }
    while (have) {
        ushortx4 u[8];
#pragma unroll
        for (int t = 0; t < 8; t++) {
            unsigned col = (unsigned)(e[t] & 0xFFFFFFFFu);
            u[t] = *(const ushortx4*)(H0 + (size_t)col * 256 + fo);
        }
        bool haveN = (j + 16 <= end);
        u64 en[8];
        if (haveN) {
#pragma unroll
            for (int t = 0; t < 8; t++) en[t] = __builtin_nontemporal_load((const u64*)&edges[j + 8 + t]);
        }
#pragma unroll
        for (int t = 0; t < 8; t++) {
            float v = __uint_as_float((unsigned)(e[t] >> 32));
            accx += v * bf2f(u[t].x);
            accy += v * bf2f(u[t].y);
            accz += v * bf2f(u[t].z);
            accw += v * bf2f(u[t].w);
        }
        j += 8;
        have = haveN;
        if (haveN) {
#pragma unroll
            for (int t = 0; t < 8; t++) e[t] = en[t];
        }
    }
    for (; j < end; j++) {
        int2 eg = edges[j];
        float v = __int_as_float(eg.y);
        ushortx4 u = *(const ushortx4*)(H0 + (size_t)eg.x * 256 + fo);
        accx += v * bf2f(u.x);
        accy += v * bf2f(u.y);
        accz += v * bf2f(u.z);
        accw += v * bf2f(u.w);
    }
    floatx4 o;
    o.x = fmaxf(accx, 0.f); o.y = fmaxf(accy, 0.f);
    o.z = fmaxf(accz, 0.f); o.w = fmaxf(accw, 0.f);
    __builtin_nontemporal_store(o, (floatx4*)(H1 + (size_t)i * 256 + fo));
}

// ---------------------------------------------------------------- column stats F=256
__global__ __launch_bounds__(256) void colstats1_kernel(const float* __restrict__ H1,
                                                        float* __restrict__ sums,
                                                        float* __restrict__ sumsq,
                                                        int n, int rpb) {
    int tid = threadIdx.x;
    int r0 = blockIdx.x * rpb;
    int r1 = min(r0 + rpb, n);
    float s = 0.f, q = 0.f;
    for (int rr = r0; rr < r1; rr++) {
        float v = H1[(size_t)rr * 256 + tid];
        s += v; q += v * v;
    }
    atomicAdd(&sums[tid], s);
    atomicAdd(&sumsq[tid], q);
}

__global__ void bnparams_kernel(const float* __restrict__ sums, const float* __restrict__ sumsq,
                                const float* __restrict__ gamma, const float* __restrict__ beta,
                                float* __restrict__ scale, float* __restrict__ shift,
                                int C, float invN) {
    int c = threadIdx.x;
    if (c < C) {
        float mean = sums[c] * invN;
        float var  = sumsq[c] * invN - mean * mean;
        float rstd = rsqrtf(var + EPS);
        float sc   = gamma[c] * rstd;
        scale[c] = sc;
        shift[c] = beta[c] - mean * sc;
    }
}

// ---------------------------------------------------------------- GEMM2: relu(bn1(H1)) @ W2 -> bf16
__global__ __launch_bounds__(256) void gemm2_kernel(const float* __restrict__ H1,
                                                    const float* __restrict__ W2,
                                                    const float* __restrict__ scale1,
                                                    const float* __restrict__ shift1,
                                                    unsigned short* __restrict__ H2, int M) {
    __shared__ float As[8][129];
    __shared__ float Bs[8][64];
    int tid = threadIdx.x;
    int tx = tid & 15, ty = tid >> 4;
    int rowBase = blockIdx.x * 128;
    float acc[8][4];
#pragma unroll
    for (int i = 0; i < 8; i++)
#pragma unroll
        for (int j = 0; j < 4; j++) acc[i][j] = 0.0f;

    int r   = tid >> 1;
    int kq  = (tid & 1) * 4;
    int bkk = tid >> 6;
    int bcol = tid & 63;

    for (int k0 = 0; k0 < 256; k0 += 8) {
        float4 a4 = make_float4(0.f, 0.f, 0.f, 0.f);
        int arow = rowBase + r;
        if (arow < M) a4 = *(const float4*)(H1 + (size_t)arow * 256 + k0 + kq);
        float av[4] = {a4.x, a4.y, a4.z, a4.w};
#pragma unroll
        for (int jj = 0; jj < 4; jj++) {
            int kk = k0 + kq + jj;
            float t = av[jj] * scale1[kk] + shift1[kk];
            As[kq + jj][r] = fmaxf(t, 0.0f);
        }
        Bs[bkk][bcol]     = W2[(size_t)(k0 + bkk) * 64 + bcol];
        Bs[bkk + 4][bcol] = W2[(size_t)(k0 + bkk + 4) * 64 + bcol];
        __syncthreads();
#pragma unroll
        for (int k = 0; k < 8; k++) {
            float ra[8], rb[4];
#pragma unroll
            for (int i = 0; i < 8; i++) ra[i] = As[k][ty * 8 + i];
#pragma unroll
            for (int j = 0; j < 4; j++) rb[j] = Bs[k][tx * 4 + j];
#pragma unroll
            for (int i = 0; i < 8; i++)
#pragma unroll
                for (int j = 0; j < 4; j++) acc[i][j] += ra[i] * rb[j];
        }
        __syncthreads();
    }
#pragma unroll
    for (int i = 0; i < 8; i++) {
        int crow = rowBase + ty * 8 + i;
        if (crow < M) {
            ushortx4 o;
            o.x = f2bf(acc[i][0]); o.y = f2bf(acc[i][1]);
            o.z = f2bf(acc[i][2]); o.w = f2bf(acc[i][3]);
            *(ushortx4*)(H2 + (size_t)crow * 64 + tx * 4) = o;
        }
    }
}

// ---------------------------------------------------------------- SpMM2 (F=64): half-wave per row, bf16 gather.
// Same pipelining + nt policy as agg1 (H2 = 12.8MB gather target stays hot).
__global__ __launch_bounds__(256) void agg2_kernel(const unsigned short* __restrict__ H2,
                                                   const int* __restrict__ rs,
                                                   const int2* __restrict__ edges,
                                                   float* __restrict__ H3, int n) {
    int w = threadIdx.x >> 6, lane = threadIdx.x & 63;
    int half = lane >> 5, sub = lane & 31;
    int i = blockIdx.x * 8 + w * 2 + half;
    if (i >= n) return;
    int start = rs[i], end = rs[i + 1];
    int fo = sub << 1;
    float accx = 0.f, accy = 0.f;
    int j = start;
    u64 e[4];
    bool have = (j + 4 <= end);
    if (have) {
#pragma unroll
        for (int t = 0; t < 4; t++) e[t] = __builtin_nontemporal_load((const u64*)&edges[j + t]);
    }
    while (have) {
        ushortx2 u[4];
#pragma unroll
        for (int t = 0; t < 4; t++) {
            unsigned col = (unsigned)(e[t] & 0xFFFFFFFFu);
            u[t] = *(const ushortx2*)(H2 + (size_t)col * 64 + fo);
        }
        bool haveN = (j + 8 <= end);
        u64 en[4];
        if (haveN) {
#pragma unroll
            for (int t = 0; t < 4; t++) en[t] = __builtin_nontemporal_load((const u64*)&edges[j + 4 + t]);
        }
#pragma unroll
        for (int t = 0; t < 4; t++) {
            float v = __uint_as_float((unsigned)(e[t] >> 32));
            accx += v * bf2f(u[t].x);
            accy += v * bf2f(u[t].y);
        }
        j += 4;
        have = haveN;
        if (haveN) {
#pragma unroll
            for (int t = 0; t < 4; t++) e[t] = en[t];
        }
    }
    for (; j < end; j++) {
        int2 eg = edges[j];
        float v = __int_as_float(eg.y);
        ushortx2 u = *(const ushortx2*)(H2 + (size_t)eg.x * 64 + fo);
        accx += v * bf2f(u.x);
        accy += v * bf2f(u.y);
    }
    floatx2 o;
    o.x = fmaxf(accx, 0.f);
    o.y = fmaxf(accy, 0.f);
    __builtin_nontemporal_store(o, (floatx2*)(H3 + (size_t)i * 64 + fo));
}

// ---------------------------------------------------------------- column stats F=64
__global__ __launch_bounds__(256) void colstats2_kernel(const float* __restrict__ H3,
                                                        float* __restrict__ sums,
                                                        float* __restrict__ sumsq,
                                                        int n, int rpb) {
    int c = threadIdx.x & 63, rsub = threadIdx.x >> 6;
    int base = blockIdx.x * rpb;
    int r1 = min(base + rpb, n);
    float s = 0.f, q = 0.f;
    for (int rr = base + rsub; rr < r1; rr += 4) {
        float v = H3[(size_t)rr * 64 + c];
        s += v; q += v * v;
    }
    atomicAdd(&sums[c], s);
    atomicAdd(&sumsq[c], q);
}

__global__ void bnapply_kernel(float* __restrict__ out, const float* __restrict__ scale,
                               const float* __restrict__ shift, int total) {
    int idx = blockIdx.x * 256 + threadIdx.x;
    if (idx < total) {
        int c = idx & 63;
        out[idx] = out[idx] * scale[c] + shift[c];
    }
}

// ---------------------------------------------------------------- launch
extern "C" void kernel_launch(void* const* d_in, const int* in_sizes, int n_in,
                              void* d_out, int out_size, void* d_ws, size_t ws_size,
                              hipStream_t stream) {
    const float* x    = (const float*)d_in[0];
    const int*   erow = (const int*)d_in[1];
    const int*   ecol = (const int*)d_in[2];
    const float* ev   = (const float*)d_in[3];
    const float* W1   = (const float*)d_in[4];
    const float* g1   = (const float*)d_in[5];
    const float* b1   = (const float*)d_in[6];
    const float* W2   = (const float*)d_in[7];
    const float* g2   = (const float*)d_in[8];
    const float* b2   = (const float*)d_in[9];
    float* out = (float*)d_out;

    int n = in_sizes[0] / 512;   // 100000
    int E = in_sizes[1];         // 3200000
    int nb = (n + 127) >> 7;     // 782 buckets of 128 rows

    char* ws = (char*)d_ws;
    size_t off = 0;
    auto alloc = [&](size_t bytes) { size_t o = off; off += (bytes + 255) & ~(size_t)255; return o; };

    int*   row_counts    = (int*)(ws + alloc((size_t)n * 4));
    int*   row_start     = (int*)(ws + alloc((size_t)(n + 1) * 4));
    int*   bucket_cursor = (int*)(ws + alloc((size_t)nb * 16 * 4));
    int2*  tmp           = (int2*)(ws + alloc((size_t)E * 8));
    int2*  edges         = (int2*)(ws + alloc((size_t)E * 8));
    unsigned short* h0  = (unsigned short*)(ws + alloc((size_t)n * 256 * 2));
    float* h1           = (float*)(ws + alloc((size_t)n * 256 * 4));
    unsigned short* h2  = (unsigned short*)(ws + alloc((size_t)n * 64 * 2));
    unsigned short* w1hi = (unsigned short*)(ws + alloc((size_t)256 * 512 * 2));
    unsigned short* w1lo = (unsigned short*)(ws + alloc((size_t)256 * 512 * 2));
    float* stats        = (float*)(ws + alloc(2048 * 4));
    float* sums1  = stats;
    float* sumsq1 = stats + 256;
    float* sums2  = stats + 512;
    float* sumsq2 = stats + 576;
    float* scale1 = stats + 640;
    float* shift1 = stats + 896;
    float* scale2 = stats + 1152;
    float* shift2 = stats + 1216;

    float invN = 1.0f / (float)n;

    // 1. zero row counts + stat accumulators (bucket_cursor fully written by scan)
    zero_kernel<<<dim3((n + 255) / 256), dim3(256), 0, stream>>>(row_counts, stats, n, 640);
    // 2. per-row degree histogram (global atomics, counter array is L2-resident)
    count_kernel<<<dim3(2048), dim3(256), 0, stream>>>(erow, row_counts, E);
    // 3. exclusive scan -> row_start + per-bucket append cursors
    row_scan_kernel<<<dim3(1), dim3(1024), 0, stream>>>(row_counts, row_start, bucket_cursor, n, E);
    // 4. pass 1: line-dense append into per-bucket staging regions
    bucket_scatter_kernel<<<dim3(2048), dim3(256), 0, stream>>>(erow, ecol, ev, bucket_cursor, tmp, E);
    // 5. pass 2: exact CSR placement within each bucket's 32KB window
    place_kernel<<<dim3(nb), dim3(256), 0, stream>>>(tmp, row_start, edges, n, E);
    // 6. W1 -> split bf16 transposed
    prep_w1_kernel<<<dim3(512), dim3(256), 0, stream>>>(W1, w1hi, w1lo);
    // 7. h0(bf16) = x @ W1  (split-bf16 MFMA, ~fp32 accurate)
    gemm1_mfma_kernel<<<dim3(2, (n + 127) / 128), dim3(256), 0, stream>>>(x, w1hi, w1lo, h0, n);
    // 8. h1 = relu(spmm(h0))  (bf16 gather, fp32 accum)
    agg1_kernel<<<dim3((n + 3) / 4), dim3(256), 0, stream>>>(h0, row_start, edges, h1, n);
    // 9. BN1 stats
    colstats1_kernel<<<dim3(400), dim3(256), 0, stream>>>(h1, sums1, sumsq1, n, (n + 399) / 400);
    // 10. BN1 params
    bnparams_kernel<<<dim3(1), dim3(256), 0, stream>>>(sums1, sumsq1, g1, b1, scale1, shift1, 256, invN);
    // 11. h2(bf16) = relu(bn1(h1)) @ W2  (fp32 vector ALU, exact)
    gemm2_kernel<<<dim3((n + 127) / 128), dim3(256), 0, stream>>>(h1, W2, scale1, shift1, h2, n);
    // 12. out_pre = relu(spmm(h2))  (bf16 gather, written into d_out)
    agg2_kernel<<<dim3((n + 7) / 8), dim3(256), 0, stream>>>(h2, row_start, edges, out, n);
    // 13. BN2 stats
    colstats2_kernel<<<dim3(200), dim3(256), 0, stream>>>(out, sums2, sumsq2, n, (n + 199) / 200);
    // 14. BN2 params
    bnparams_kernel<<<dim3(1), dim3(64), 0, stream>>>(sums2, sumsq2, g2, b2, scale2, shift2, 64, invN);
    // 15. in-place BN apply on d_out
    bnapply_kernel<<<dim3((n * 64 + 255) / 256), dim3(256), 0, stream>>>(out, scale2, shift2, n * 64);

    (void)n_in; (void)out_size; (void)ws_size;
}

// Round 4
// 1354.994 us; speedup vs baseline: 1.0879x; 1.0879x over previous
//
#include <hip/hip_runtime.h>

#define EPS 1e-5f

typedef __attribute__((ext_vector_type(8))) short short8;
typedef __attribute__((ext_vector_type(4))) float floatx4;
typedef __attribute__((ext_vector_type(4))) unsigned short ushortx4;
typedef __attribute__((ext_vector_type(2))) unsigned short ushortx2;

__device__ __forceinline__ unsigned short f2bf(float f) {
    unsigned u = __float_as_uint(f);
    unsigned r = (u + 0x7FFFu + ((u >> 16) & 1u)) >> 16;
    return (unsigned short)r;
}
__device__ __forceinline__ float bf2f(unsigned short h) {
    return __uint_as_float((unsigned)h << 16);
}

// ---------------------------------------------------------------- utilities
// zero per-row counts + stat accumulators (both re-derived every call)
__global__ void zero_kernel(int* __restrict__ counts, float* __restrict__ stats,
                            int n_counts, int n_stats) {
    int i = blockIdx.x * 256 + threadIdx.x;
    if (i < n_counts) counts[i] = 0;
    if (i < n_stats)  stats[i] = 0.0f;
}

// per-row degree count (400KB counter array, L2-resident)
__global__ __launch_bounds__(256) void count_kernel(const int* __restrict__ erow,
                                                    int* __restrict__ counts, int E) {
    int stride = gridDim.x * 256;
    for (int j = blockIdx.x * 256 + threadIdx.x; j < E; j += stride)
        atomicAdd(&counts[erow[j]], 1);
}

// single-block exclusive scan over counts[n] -> row_start[n+1].
// Also emits bucket append-cursors at 128-row boundaries (one per 64B line):
// bucket_cursor[b*16] = row_start[b*128].  Single source of truth: row_start.
__global__ __launch_bounds__(1024) void row_scan_kernel(const int* __restrict__ counts,
                                                        int* __restrict__ row_start,
                                                        int* __restrict__ bucket_cursor,
                                                        int n, int E) {
    __shared__ int lds[1024];
    int t = threadIdx.x;
    int per = (n + 1023) >> 10;
    int s0 = t * per, s1 = min(s0 + per, n);
    int sum = 0;
    for (int i = s0; i < s1; i++) sum += counts[i];
    lds[t] = sum;
    __syncthreads();
    for (int off = 1; off < 1024; off <<= 1) {
        int v = (t >= off) ? lds[t - off] : 0;
        __syncthreads();
        lds[t] += v;
        __syncthreads();
    }
    int run = lds[t] - sum;  // exclusive prefix of this thread's strip
    for (int i = s0; i < s1; i++) {
        row_start[i] = run;
        if ((i & 127) == 0) bucket_cursor[(i >> 7) * 16] = run;
        run += counts[i];
    }
    if (t == 0) row_start[n] = E;
}

// pass 1: append edges into their bucket's region of the staging array.
// Appends to a bucket are temporally dense -> write frontier is one hot line
// per bucket -> ~1x write amplification (vs 8x for row-random scatter).
// key packs localrow (7b) above col (17b).  Region overflow impossible:
// appends per bucket == region size by construction.
__global__ __launch_bounds__(256) void bucket_scatter_kernel(const int* __restrict__ erow,
                                                             const int* __restrict__ ecol,
                                                             const float* __restrict__ ev,
                                                             int* __restrict__ bucket_cursor,
                                                             int2* __restrict__ tmp, int E) {
    int stride = gridDim.x * 256;
    for (int j = blockIdx.x * 256 + threadIdx.x; j < E; j += stride) {
        int r = erow[j];
        int b = r >> 7, lr = r & 127;
        int p = atomicAdd(&bucket_cursor[b * 16], 1);
        tmp[p] = make_int2(ecol[j] | (lr << 17), __float_as_int(ev[j]));
    }
}

// pass 2: one block per bucket. Exact CSR placement using LDS cursors
// initialized directly from row_start (no re-derivation). All writes fall in
// the block's own ~32KB window -> L2-hot, full-line evictions.
__global__ __launch_bounds__(256) void place_kernel(const int2* __restrict__ tmp,
                                                    const int* __restrict__ row_start,
                                                    int2* __restrict__ edges,
                                                    int n, int E) {
    __shared__ int cur[128];
    int b = blockIdx.x, t = threadIdx.x;
    int rbase = b << 7;
    int rend  = min(rbase + 128, n);
    int bstart = row_start[rbase];
    int bend   = row_start[rend];
    if (t < 128) {
        int r = rbase + t;
        cur[t] = (r < n) ? row_start[r] : E;   // rows past n never referenced
    }
    __syncthreads();
    for (int j = bstart + t; j < bend; j += 256) {
        int2 e = tmp[j];
        int lr = ((unsigned)e.x) >> 17;
        int pos = atomicAdd(&cur[lr], 1);
        edges[pos] = make_int2(e.x & 0x1FFFF, e.y);
    }
}

// ---------------------------------------------------------------- W1 -> split bf16 transposed [256][512]
__global__ void prep_w1_kernel(const float* __restrict__ W1,
                               unsigned short* __restrict__ Bhi,
                               unsigned short* __restrict__ Blo) {
    int idx = blockIdx.x * 256 + threadIdx.x;   // 131072 total
    int nn = idx >> 9, k = idx & 511;
    float w = W1[(size_t)k * 256 + nn];
    unsigned short hi = f2bf(w);
    float rem = w - bf2f(hi);
    Bhi[idx] = hi;
    Blo[idx] = f2bf(rem);
}

// ---------------------------------------------------------------- GEMM1 (split-bf16 MFMA, ~fp32 exact):
// h0[M,256](bf16) = A[M,512](fp32) @ W1.  acc += ah*bh + al*bh + ah*bl.
__global__ __launch_bounds__(256) void gemm1_mfma_kernel(const float* __restrict__ A,
                                                         const unsigned short* __restrict__ Bhi,
                                                         const unsigned short* __restrict__ Blo,
                                                         unsigned short* __restrict__ H0, int M) {
    __shared__ unsigned short AsH[128][32];
    __shared__ unsigned short AsL[128][32];
    __shared__ unsigned short BsH[128][32];
    __shared__ unsigned short BsL[128][32];
    int tid  = threadIdx.x;
    int lane = tid & 63, w = tid >> 6;
    int wm = w & 1, wn = w >> 1;
    int rowBase = blockIdx.y * 128;
    int colBase = blockIdx.x * 128;

    floatx4 acc[4][4];
#pragma unroll
    for (int i = 0; i < 4; i++)
#pragma unroll
        for (int j = 0; j < 4; j++)
#pragma unroll
            for (int r = 0; r < 4; r++) acc[i][j][r] = 0.0f;

    int r    = tid >> 1;
    int half = tid & 1;
    bool aval = (rowBase + r) < M;
    const float* aptr = A + (size_t)(rowBase + r) * 512 + half * 16;
    const unsigned short* bhptr = Bhi + (size_t)(colBase + r) * 512 + half * 16;
    const unsigned short* blptr = Blo + (size_t)(colBase + r) * 512 + half * 16;

    int cl = lane & 15, quad = lane >> 4;
    int q8 = quad * 8;

    for (int k0 = 0; k0 < 512; k0 += 32) {
        float f[16];
        if (aval) {
            *(float4*)&f[0]  = *(const float4*)(aptr + k0);
            *(float4*)&f[4]  = *(const float4*)(aptr + k0 + 4);
            *(float4*)&f[8]  = *(const float4*)(aptr + k0 + 8);
            *(float4*)&f[12] = *(const float4*)(aptr + k0 + 12);
        } else {
#pragma unroll
            for (int t = 0; t < 16; t++) f[t] = 0.0f;
        }
        union { unsigned short s[16]; uint4 q[2]; } ph, pl;
#pragma unroll
        for (int t = 0; t < 16; t++) {
            unsigned short hi = f2bf(f[t]);
            ph.s[t] = hi;
            pl.s[t] = f2bf(f[t] - bf2f(hi));
        }
        *(uint4*)&AsH[r][half * 16]     = ph.q[0];
        *(uint4*)&AsH[r][half * 16 + 8] = ph.q[1];
        *(uint4*)&AsL[r][half * 16]     = pl.q[0];
        *(uint4*)&AsL[r][half * 16 + 8] = pl.q[1];
        *(uint4*)&BsH[r][half * 16]     = *(const uint4*)(bhptr + k0);
        *(uint4*)&BsH[r][half * 16 + 8] = *(const uint4*)(bhptr + k0 + 8);
        *(uint4*)&BsL[r][half * 16]     = *(const uint4*)(blptr + k0);
        *(uint4*)&BsL[r][half * 16 + 8] = *(const uint4*)(blptr + k0 + 8);
        __syncthreads();

        short8 ah[4], al[4], bh[4], bl[4];
#pragma unroll
        for (int mt = 0; mt < 4; mt++) {
            ah[mt] = *(short8*)&AsH[wm * 64 + mt * 16 + cl][q8];
            al[mt] = *(short8*)&AsL[wm * 64 + mt * 16 + cl][q8];
        }
#pragma unroll
        for (int nt = 0; nt < 4; nt++) {
            bh[nt] = *(short8*)&BsH[wn * 64 + nt * 16 + cl][q8];
            bl[nt] = *(short8*)&BsL[wn * 64 + nt * 16 + cl][q8];
        }
#pragma unroll
        for (int mt = 0; mt < 4; mt++)
#pragma unroll
            for (int nt = 0; nt < 4; nt++) {
                acc[mt][nt] = __builtin_amdgcn_mfma_f32_16x16x32_bf16(ah[mt], bh[nt], acc[mt][nt], 0, 0, 0);
                acc[mt][nt] = __builtin_amdgcn_mfma_f32_16x16x32_bf16(al[mt], bh[nt], acc[mt][nt], 0, 0, 0);
                acc[mt][nt] = __builtin_amdgcn_mfma_f32_16x16x32_bf16(ah[mt], bl[nt], acc[mt][nt], 0, 0, 0);
            }
        __syncthreads();
    }

#pragma unroll
    for (int mt = 0; mt < 4; mt++) {
#pragma unroll
        for (int reg = 0; reg < 4; reg++) {
            int gr = rowBase + wm * 64 + mt * 16 + quad * 4 + reg;
            if (gr < M) {
#pragma unroll
                for (int nt = 0; nt < 4; nt++) {
                    H0[(size_t)gr * 256 + colBase + wn * 64 + nt * 16 + cl] = f2bf(acc[mt][nt][reg]);
                }
            }
        }
    }
}

// ---------------------------------------------------------------- SpMM1 (F=256, split into 2 half-F passes):
// gridDim.y = 2 halves of the feature dim; linear block dispatch order runs
// all y=0 blocks before y=1, so each soft-pass gathers from a 25.6MB slice
// of H0 (vs 51.2MB) -> L3-resident under streaming pressure.
// 32-lane group per row-half, 8 B/lane gathers (same coalescing as before).
__global__ __launch_bounds__(256) void agg1_kernel(const unsigned short* __restrict__ H0,
                                                   const int* __restrict__ rs,
                                                   const int2* __restrict__ edges,
                                                   float* __restrict__ H1, int n) {
    int g = threadIdx.x >> 5, sub = threadIdx.x & 31;
    int i = blockIdx.x * 8 + g;
    if (i >= n) return;
    int start = rs[i], end = rs[i + 1];
    int fo = blockIdx.y * 128 + (sub << 2);
    float accx = 0.f, accy = 0.f, accz = 0.f, accw = 0.f;
    int j = start;
    for (; j + 8 <= end; j += 8) {
        int2 e[8];
        ushortx4 u[8];
#pragma unroll
        for (int t = 0; t < 8; t++) e[t] = edges[j + t];
#pragma unroll
        for (int t = 0; t < 8; t++)
            u[t] = *(const ushortx4*)(H0 + (size_t)e[t].x * 256 + fo);
#pragma unroll
        for (int t = 0; t < 8; t++) {
            float v = __int_as_float(e[t].y);
            accx += v * bf2f(u[t].x);
            accy += v * bf2f(u[t].y);
            accz += v * bf2f(u[t].z);
            accw += v * bf2f(u[t].w);
        }
    }
    for (; j < end; j++) {
        int2 e = edges[j];
        float v = __int_as_float(e.y);
        ushortx4 u = *(const ushortx4*)(H0 + (size_t)e.x * 256 + fo);
        accx += v * bf2f(u.x);
        accy += v * bf2f(u.y);
        accz += v * bf2f(u.z);
        accw += v * bf2f(u.w);
    }
    float4 o;
    o.x = fmaxf(accx, 0.f); o.y = fmaxf(accy, 0.f);
    o.z = fmaxf(accz, 0.f); o.w = fmaxf(accw, 0.f);
    *(float4*)(H1 + (size_t)i * 256 + fo) = o;
}

// ---------------------------------------------------------------- column stats F=256
__global__ __launch_bounds__(256) void colstats1_kernel(const float* __restrict__ H1,
                                                        float* __restrict__ sums,
                                                        float* __restrict__ sumsq,
                                                        int n, int rpb) {
    int tid = threadIdx.x;
    int r0 = blockIdx.x * rpb;
    int r1 = min(r0 + rpb, n);
    float s = 0.f, q = 0.f;
    for (int rr = r0; rr < r1; rr++) {
        float v = H1[(size_t)rr * 256 + tid];
        s += v; q += v * v;
    }
    atomicAdd(&sums[tid], s);
    atomicAdd(&sumsq[tid], q);
}

__global__ void bnparams_kernel(const float* __restrict__ sums, const float* __restrict__ sumsq,
                                const float* __restrict__ gamma, const float* __restrict__ beta,
                                float* __restrict__ scale, float* __restrict__ shift,
                                int C, float invN) {
    int c = threadIdx.x;
    if (c < C) {
        float mean = sums[c] * invN;
        float var  = sumsq[c] * invN - mean * mean;
        float rstd = rsqrtf(var + EPS);
        float sc   = gamma[c] * rstd;
        scale[c] = sc;
        shift[c] = beta[c] - mean * sc;
    }
}

// ---------------------------------------------------------------- GEMM2: relu(bn1(H1)) @ W2 -> bf16
__global__ __launch_bounds__(256) void gemm2_kernel(const float* __restrict__ H1,
                                                    const float* __restrict__ W2,
                                                    const float* __restrict__ scale1,
                                                    const float* __restrict__ shift1,
                                                    unsigned short* __restrict__ H2, int M) {
    __shared__ float As[8][129];
    __shared__ float Bs[8][64];
    int tid = threadIdx.x;
    int tx = tid & 15, ty = tid >> 4;
    int rowBase = blockIdx.x * 128;
    float acc[8][4];
#pragma unroll
    for (int i = 0; i < 8; i++)
#pragma unroll
        for (int j = 0; j < 4; j++) acc[i][j] = 0.0f;

    int r   = tid >> 1;
    int kq  = (tid & 1) * 4;
    int bkk = tid >> 6;
    int bcol = tid & 63;

    for (int k0 = 0; k0 < 256; k0 += 8) {
        float4 a4 = make_float4(0.f, 0.f, 0.f, 0.f);
        int arow = rowBase + r;
        if (arow < M) a4 = *(const float4*)(H1 + (size_t)arow * 256 + k0 + kq);
        float av[4] = {a4.x, a4.y, a4.z, a4.w};
#pragma unroll
        for (int jj = 0; jj < 4; jj++) {
            int kk = k0 + kq + jj;
            float t = av[jj] * scale1[kk] + shift1[kk];
            As[kq + jj][r] = fmaxf(t, 0.0f);
        }
        Bs[bkk][bcol]     = W2[(size_t)(k0 + bkk) * 64 + bcol];
        Bs[bkk + 4][bcol] = W2[(size_t)(k0 + bkk + 4) * 64 + bcol];
        __syncthreads();
#pragma unroll
        for (int k = 0; k < 8; k++) {
            float ra[8], rb[4];
#pragma unroll
            for (int i = 0; i < 8; i++) ra[i] = As[k][ty * 8 + i];
#pragma unroll
            for (int j = 0; j < 4; j++) rb[j] = Bs[k][tx * 4 + j];
#pragma unroll
            for (int i = 0; i < 8; i++)
#pragma unroll
                for (int j = 0; j < 4; j++) acc[i][j] += ra[i] * rb[j];
        }
        __syncthreads();
    }
#pragma unroll
    for (int i = 0; i < 8; i++) {
        int crow = rowBase + ty * 8 + i;
        if (crow < M) {
            ushortx4 o;
            o.x = f2bf(acc[i][0]); o.y = f2bf(acc[i][1]);
            o.z = f2bf(acc[i][2]); o.w = f2bf(acc[i][3]);
            *(ushortx4*)(H2 + (size_t)crow * 64 + tx * 4) = o;
        }
    }
}

// ---------------------------------------------------------------- SpMM2 (F=64): half-wave per row, bf16 gather
__global__ __launch_bounds__(256) void agg2_kernel(const unsigned short* __restrict__ H2,
                                                   const int* __restrict__ rs,
                                                   const int2* __restrict__ edges,
                                                   float* __restrict__ H3, int n) {
    int w = threadIdx.x >> 6, lane = threadIdx.x & 63;
    int half = lane >> 5, sub = lane & 31;
    int i = blockIdx.x * 8 + w * 2 + half;
    if (i >= n) return;
    int start = rs[i], end = rs[i + 1];
    int fo = sub << 1;
    float accx = 0.f, accy = 0.f;
    int j = start;
    for (; j + 4 <= end; j += 4) {
        int2 e[4];
        ushortx2 u[4];
#pragma unroll
        for (int t = 0; t < 4; t++) e[t] = edges[j + t];
#pragma unroll
        for (int t = 0; t < 4; t++)
            u[t] = *(const ushortx2*)(H2 + (size_t)e[t].x * 64 + fo);
#pragma unroll
        for (int t = 0; t < 4; t++) {
            float v = __int_as_float(e[t].y);
            accx += v * bf2f(u[t].x);
            accy += v * bf2f(u[t].y);
        }
    }
    for (; j < end; j++) {
        int2 e = edges[j];
        float v = __int_as_float(e.y);
        ushortx2 u = *(const ushortx2*)(H2 + (size_t)e.x * 64 + fo);
        accx += v * bf2f(u.x);
        accy += v * bf2f(u.y);
    }
    float2 o;
    o.x = fmaxf(accx, 0.f);
    o.y = fmaxf(accy, 0.f);
    *(float2*)(H3 + (size_t)i * 64 + fo) = o;
}

// ---------------------------------------------------------------- column stats F=64
__global__ __launch_bounds__(256) void colstats2_kernel(const float* __restrict__ H3,
                                                        float* __restrict__ sums,
                                                        float* __restrict__ sumsq,
                                                        int n, int rpb) {
    int c = threadIdx.x & 63, rsub = threadIdx.x >> 6;
    int base = blockIdx.x * rpb;
    int r1 = min(base + rpb, n);
    float s = 0.f, q = 0.f;
    for (int rr = base + rsub; rr < r1; rr += 4) {
        float v = H3[(size_t)rr * 64 + c];
        s += v; q += v * v;
    }
    atomicAdd(&sums[c], s);
    atomicAdd(&sumsq[c], q);
}

__global__ void bnapply_kernel(float* __restrict__ out, const float* __restrict__ scale,
                               const float* __restrict__ shift, int total) {
    int idx = blockIdx.x * 256 + threadIdx.x;
    if (idx < total) {
        int c = idx & 63;
        out[idx] = out[idx] * scale[c] + shift[c];
    }
}

// ---------------------------------------------------------------- launch
extern "C" void kernel_launch(void* const* d_in, const int* in_sizes, int n_in,
                              void* d_out, int out_size, void* d_ws, size_t ws_size,
                              hipStream_t stream) {
    const float* x    = (const float*)d_in[0];
    const int*   erow = (const int*)d_in[1];
    const int*   ecol = (const int*)d_in[2];
    const float* ev   = (const float*)d_in[3];
    const float* W1   = (const float*)d_in[4];
    const float* g1   = (const float*)d_in[5];
    const float* b1   = (const float*)d_in[6];
    const float* W2   = (const float*)d_in[7];
    const float* g2   = (const float*)d_in[8];
    const float* b2   = (const float*)d_in[9];
    float* out = (float*)d_out;

    int n = in_sizes[0] / 512;   // 100000
    int E = in_sizes[1];         // 3200000
    int nb = (n + 127) >> 7;     // 782 buckets of 128 rows

    char* ws = (char*)d_ws;
    size_t off = 0;
    auto alloc = [&](size_t bytes) { size_t o = off; off += (bytes + 255) & ~(size_t)255; return o; };

    int*   row_counts    = (int*)(ws + alloc((size_t)n * 4));
    int*   row_start     = (int*)(ws + alloc((size_t)(n + 1) * 4));
    int*   bucket_cursor = (int*)(ws + alloc((size_t)nb * 16 * 4));
    int2*  tmp           = (int2*)(ws + alloc((size_t)E * 8));
    int2*  edges         = (int2*)(ws + alloc((size_t)E * 8));
    unsigned short* h0  = (unsigned short*)(ws + alloc((size_t)n * 256 * 2));
    float* h1           = (float*)(ws + alloc((size_t)n * 256 * 4));
    unsigned short* h2  = (unsigned short*)(ws + alloc((size_t)n * 64 * 2));
    unsigned short* w1hi = (unsigned short*)(ws + alloc((size_t)256 * 512 * 2));
    unsigned short* w1lo = (unsigned short*)(ws + alloc((size_t)256 * 512 * 2));
    float* stats        = (float*)(ws + alloc(2048 * 4));
    float* sums1  = stats;
    float* sumsq1 = stats + 256;
    float* sums2  = stats + 512;
    float* sumsq2 = stats + 576;
    float* scale1 = stats + 640;
    float* shift1 = stats + 896;
    float* scale2 = stats + 1152;
    float* shift2 = stats + 1216;

    float invN = 1.0f / (float)n;

    // 1. zero row counts + stat accumulators (bucket_cursor fully written by scan)
    zero_kernel<<<dim3((n + 255) / 256), dim3(256), 0, stream>>>(row_counts, stats, n, 640);
    // 2. per-row degree histogram (global atomics, counter array is L2-resident)
    count_kernel<<<dim3(2048), dim3(256), 0, stream>>>(erow, row_counts, E);
    // 3. exclusive scan -> row_start + per-bucket append cursors
    row_scan_kernel<<<dim3(1), dim3(1024), 0, stream>>>(row_counts, row_start, bucket_cursor, n, E);
    // 4. pass 1: line-dense append into per-bucket staging regions
    bucket_scatter_kernel<<<dim3(2048), dim3(256), 0, stream>>>(erow, ecol, ev, bucket_cursor, tmp, E);
    // 5. pass 2: exact CSR placement within each bucket's 32KB window
    place_kernel<<<dim3(nb), dim3(256), 0, stream>>>(tmp, row_start, edges, n, E);
    // 6. W1 -> split bf16 transposed
    prep_w1_kernel<<<dim3(512), dim3(256), 0, stream>>>(W1, w1hi, w1lo);
    // 7. h0(bf16) = x @ W1  (split-bf16 MFMA, ~fp32 accurate)
    gemm1_mfma_kernel<<<dim3(2, (n + 127) / 128), dim3(256), 0, stream>>>(x, w1hi, w1lo, h0, n);
    // 8. h1 = relu(spmm(h0))  (bf16 gather, fp32 accum; y = feature half, soft-sequenced)
    agg1_kernel<<<dim3((n + 7) / 8, 2), dim3(256), 0, stream>>>(h0, row_start, edges, h1, n);
    // 9. BN1 stats
    colstats1_kernel<<<dim3(400), dim3(256), 0, stream>>>(h1, sums1, sumsq1, n, (n + 399) / 400);
    // 10. BN1 params
    bnparams_kernel<<<dim3(1), dim3(256), 0, stream>>>(sums1, sumsq1, g1, b1, scale1, shift1, 256, invN);
    // 11. h2(bf16) = relu(bn1(h1)) @ W2  (fp32 vector ALU, exact)
    gemm2_kernel<<<dim3((n + 127) / 128), dim3(256), 0, stream>>>(h1, W2, scale1, shift1, h2, n);
    // 12. out_pre = relu(spmm(h2))  (bf16 gather, written into d_out)
    agg2_kernel<<<dim3((n + 7) / 8), dim3(256), 0, stream>>>(h2, row_start, edges, out, n);
    // 13. BN2 stats
    colstats2_kernel<<<dim3(200), dim3(256), 0, stream>>>(out, sums2, sumsq2, n, (n + 199) / 200);
    // 14. BN2 params
    bnparams_kernel<<<dim3(1), dim3(64), 0, stream>>>(sums2, sumsq2, g2, b2, scale2, shift2, 64, invN);
    // 15. in-place BN apply on d_out
    bnapply_kernel<<<dim3((n * 64 + 255) / 256), dim3(256), 0, stream>>>(out, scale2, shift2, n * 64);

    (void)n_in; (void)out_size; (void)ws_size;
}

// Round 5
// 1104.901 us; speedup vs baseline: 1.3342x; 1.2263x over previous
//
#include <hip/hip_runtime.h>

#define EPS 1e-5f

typedef __attribute__((ext_vector_type(8))) short short8;
typedef __attribute__((ext_vector_type(4))) float floatx4;
typedef __attribute__((ext_vector_type(4))) unsigned short ushortx4;
typedef __attribute__((ext_vector_type(2))) unsigned short ushortx2;

__device__ __forceinline__ unsigned short f2bf(float f) {
    unsigned u = __float_as_uint(f);
    unsigned r = (u + 0x7FFFu + ((u >> 16) & 1u)) >> 16;
    return (unsigned short)r;
}
__device__ __forceinline__ float bf2f(unsigned short h) {
    return __uint_as_float((unsigned)h << 16);
}

// ---------------------------------------------------------------- utilities
// zero bucket histogram (782 ints) + stat accumulators; single small grid
__global__ void zero_kernel(int* __restrict__ hist, float* __restrict__ stats,
                            int nb, int n_stats) {
    int i = blockIdx.x * 256 + threadIdx.x;
    if (i < nb)      hist[i] = 0;
    if (i < n_stats) stats[i] = 0.0f;
}

// LDS-aggregated histogram of buckets (row>>7): 782 bins, near-free vs
// per-row global atomics (3.2M atomics removed).
__global__ __launch_bounds__(256) void bucket_hist_kernel(const int* __restrict__ erow,
                                                          int* __restrict__ hist,
                                                          int E, int nb) {
    __shared__ int cnt[1024];
    for (int i = threadIdx.x; i < nb; i += 256) cnt[i] = 0;
    __syncthreads();
    int stride = gridDim.x * 256;
    for (int j = blockIdx.x * 256 + threadIdx.x; j < E; j += stride)
        atomicAdd(&cnt[erow[j] >> 7], 1);
    __syncthreads();
    for (int i = threadIdx.x; i < nb; i += 256) {
        int c = cnt[i];
        if (c) atomicAdd(&hist[i], c);
    }
}

// single-block exclusive scan over hist[nb] (nb=782 <= 1024) ->
// bucket_start[nb+1] + padded append cursors. Single source of truth.
__global__ __launch_bounds__(1024) void bucket_scan_kernel(const int* __restrict__ hist,
                                                           int* __restrict__ bucket_start,
                                                           int* __restrict__ bucket_cursor,
                                                           int* __restrict__ row_start,
                                                           int nb, int n, int E) {
    __shared__ int lds[1024];
    int t = threadIdx.x;
    int v = (t < nb) ? hist[t] : 0;
    lds[t] = v;
    __syncthreads();
    for (int off = 1; off < 1024; off <<= 1) {
        int w = (t >= off) ? lds[t - off] : 0;
        __syncthreads();
        lds[t] += w;
        __syncthreads();
    }
    int ex = lds[t] - v;  // exclusive prefix
    if (t < nb) {
        bucket_start[t] = ex;
        bucket_cursor[t * 16] = ex;   // one cursor per 64B line
    }
    if (t == 0) { bucket_start[nb] = E; row_start[n] = E; }
}

// pass 1: append edges into their bucket's region of the staging array.
// Appends per bucket are temporally dense -> ~1x write amplification.
// key packs localrow (7b) above col (17b). Overflow impossible: appends per
// bucket == hist[b] == region size by construction.
__global__ __launch_bounds__(256) void bucket_scatter_kernel(const int* __restrict__ erow,
                                                             const int* __restrict__ ecol,
                                                             const float* __restrict__ ev,
                                                             int* __restrict__ bucket_cursor,
                                                             int2* __restrict__ tmp, int E) {
    int stride = gridDim.x * 256;
    for (int j = blockIdx.x * 256 + threadIdx.x; j < E; j += stride) {
        int r = erow[j];
        int b = r >> 7, lr = r & 127;
        int p = atomicAdd(&bucket_cursor[b * 16], 1);
        tmp[p] = make_int2(ecol[j] | (lr << 17), __float_as_int(ev[j]));
    }
}

// pass 2: one block per bucket. Derives per-row offsets ITSELF via LDS
// count+scan of its own region (no global per-row count/scan kernels),
// writes row_start[128 rows] and places edges exactly. Region is ~32KB,
// L2-hot for the second read.
__global__ __launch_bounds__(256) void place_kernel(const int2* __restrict__ tmp,
                                                    const int* __restrict__ bucket_start,
                                                    int* __restrict__ row_start,
                                                    int2* __restrict__ edges, int n) {
    __shared__ int cnt[128], scn[128], cur[128];
    int b = blockIdx.x, t = threadIdx.x;
    int bstart = bucket_start[b], bend = bucket_start[b + 1];
    if (t < 128) cnt[t] = 0;
    __syncthreads();
    for (int j = bstart + t; j < bend; j += 256)
        atomicAdd(&cnt[((unsigned)tmp[j].x) >> 17], 1);
    __syncthreads();
    if (t < 128) scn[t] = cnt[t];
    __syncthreads();
#pragma unroll
    for (int off = 1; off < 128; off <<= 1) {
        int v = 0;
        if (t < 128 && t >= off) v = scn[t - off];
        __syncthreads();
        if (t < 128) scn[t] += v;
        __syncthreads();
    }
    if (t < 128) {
        int pref = bstart + scn[t] - cnt[t];   // exclusive prefix within bucket
        cur[t] = pref;
        int r = b * 128 + t;
        if (r < n) row_start[r] = pref;
    }
    __syncthreads();
    for (int j = bstart + t; j < bend; j += 256) {
        int2 e = tmp[j];
        int lr = ((unsigned)e.x) >> 17;
        int pos = atomicAdd(&cur[lr], 1);
        edges[pos] = make_int2(e.x & 0x1FFFF, e.y);
    }
}

// ---------------------------------------------------------------- W1 -> split bf16 transposed [256][512]
__global__ void prep_w1_kernel(const float* __restrict__ W1,
                               unsigned short* __restrict__ Bhi,
                               unsigned short* __restrict__ Blo) {
    int idx = blockIdx.x * 256 + threadIdx.x;   // 131072 total
    int nn = idx >> 9, k = idx & 511;
    float w = W1[(size_t)k * 256 + nn];
    unsigned short hi = f2bf(w);
    float rem = w - bf2f(hi);
    Bhi[idx] = hi;
    Blo[idx] = f2bf(rem);
}

// ---------------------------------------------------------------- GEMM1 (split-bf16 MFMA, ~fp32 exact):
// h0[M,256](bf16) = A[M,512](fp32) @ W1.  acc += ah*bh + al*bh + ah*bl.
__global__ __launch_bounds__(256) void gemm1_mfma_kernel(const float* __restrict__ A,
                                                         const unsigned short* __restrict__ Bhi,
                                                         const unsigned short* __restrict__ Blo,
                                                         unsigned short* __restrict__ H0, int M) {
    __shared__ unsigned short AsH[128][32];
    __shared__ unsigned short AsL[128][32];
    __shared__ unsigned short BsH[128][32];
    __shared__ unsigned short BsL[128][32];
    int tid  = threadIdx.x;
    int lane = tid & 63, w = tid >> 6;
    int wm = w & 1, wn = w >> 1;
    int rowBase = blockIdx.y * 128;
    int colBase = blockIdx.x * 128;

    floatx4 acc[4][4];
#pragma unroll
    for (int i = 0; i < 4; i++)
#pragma unroll
        for (int j = 0; j < 4; j++)
#pragma unroll
            for (int r = 0; r < 4; r++) acc[i][j][r] = 0.0f;

    int r    = tid >> 1;
    int half = tid & 1;
    bool aval = (rowBase + r) < M;
    const float* aptr = A + (size_t)(rowBase + r) * 512 + half * 16;
    const unsigned short* bhptr = Bhi + (size_t)(colBase + r) * 512 + half * 16;
    const unsigned short* blptr = Blo + (size_t)(colBase + r) * 512 + half * 16;

    int cl = lane & 15, quad = lane >> 4;
    int q8 = quad * 8;

    for (int k0 = 0; k0 < 512; k0 += 32) {
        float f[16];
        if (aval) {
            *(float4*)&f[0]  = *(const float4*)(aptr + k0);
            *(float4*)&f[4]  = *(const float4*)(aptr + k0 + 4);
            *(float4*)&f[8]  = *(const float4*)(aptr + k0 + 8);
            *(float4*)&f[12] = *(const float4*)(aptr + k0 + 12);
        } else {
#pragma unroll
            for (int t = 0; t < 16; t++) f[t] = 0.0f;
        }
        union { unsigned short s[16]; uint4 q[2]; } ph, pl;
#pragma unroll
        for (int t = 0; t < 16; t++) {
            unsigned short hi = f2bf(f[t]);
            ph.s[t] = hi;
            pl.s[t] = f2bf(f[t] - bf2f(hi));
        }
        *(uint4*)&AsH[r][half * 16]     = ph.q[0];
        *(uint4*)&AsH[r][half * 16 + 8] = ph.q[1];
        *(uint4*)&AsL[r][half * 16]     = pl.q[0];
        *(uint4*)&AsL[r][half * 16 + 8] = pl.q[1];
        *(uint4*)&BsH[r][half * 16]     = *(const uint4*)(bhptr + k0);
        *(uint4*)&BsH[r][half * 16 + 8] = *(const uint4*)(bhptr + k0 + 8);
        *(uint4*)&BsL[r][half * 16]     = *(const uint4*)(blptr + k0);
        *(uint4*)&BsL[r][half * 16 + 8] = *(const uint4*)(blptr + k0 + 8);
        __syncthreads();

        short8 ah[4], al[4], bh[4], bl[4];
#pragma unroll
        for (int mt = 0; mt < 4; mt++) {
            ah[mt] = *(short8*)&AsH[wm * 64 + mt * 16 + cl][q8];
            al[mt] = *(short8*)&AsL[wm * 64 + mt * 16 + cl][q8];
        }
#pragma unroll
        for (int nt = 0; nt < 4; nt++) {
            bh[nt] = *(short8*)&BsH[wn * 64 + nt * 16 + cl][q8];
            bl[nt] = *(short8*)&BsL[wn * 64 + nt * 16 + cl][q8];
        }
#pragma unroll
        for (int mt = 0; mt < 4; mt++)
#pragma unroll
            for (int nt = 0; nt < 4; nt++) {
                acc[mt][nt] = __builtin_amdgcn_mfma_f32_16x16x32_bf16(ah[mt], bh[nt], acc[mt][nt], 0, 0, 0);
                acc[mt][nt] = __builtin_amdgcn_mfma_f32_16x16x32_bf16(al[mt], bh[nt], acc[mt][nt], 0, 0, 0);
                acc[mt][nt] = __builtin_amdgcn_mfma_f32_16x16x32_bf16(ah[mt], bl[nt], acc[mt][nt], 0, 0, 0);
            }
        __syncthreads();
    }

#pragma unroll
    for (int mt = 0; mt < 4; mt++) {
#pragma unroll
        for (int reg = 0; reg < 4; reg++) {
            int gr = rowBase + wm * 64 + mt * 16 + quad * 4 + reg;
            if (gr < M) {
#pragma unroll
                for (int nt = 0; nt < 4; nt++) {
                    H0[(size_t)gr * 256 + colBase + wn * 64 + nt * 16 + cl] = f2bf(acc[mt][nt][reg]);
                }
            }
        }
    }
}

// ---------------------------------------------------------------- SpMM1 (F=256, split into 2 half-F passes):
// gridDim.y = 2 halves of the feature dim (soft-sequenced by dispatch order);
// 32-lane group per row-half, 8 B/lane gathers.
__global__ __launch_bounds__(256) void agg1_kernel(const unsigned short* __restrict__ H0,
                                                   const int* __restrict__ rs,
                                                   const int2* __restrict__ edges,
                                                   float* __restrict__ H1, int n) {
    int g = threadIdx.x >> 5, sub = threadIdx.x & 31;
    int i = blockIdx.x * 8 + g;
    if (i >= n) return;
    int start = rs[i], end = rs[i + 1];
    int fo = blockIdx.y * 128 + (sub << 2);
    float accx = 0.f, accy = 0.f, accz = 0.f, accw = 0.f;
    int j = start;
    for (; j + 8 <= end; j += 8) {
        int2 e[8];
        ushortx4 u[8];
#pragma unroll
        for (int t = 0; t < 8; t++) e[t] = edges[j + t];
#pragma unroll
        for (int t = 0; t < 8; t++)
            u[t] = *(const ushortx4*)(H0 + (size_t)e[t].x * 256 + fo);
#pragma unroll
        for (int t = 0; t < 8; t++) {
            float v = __int_as_float(e[t].y);
            accx += v * bf2f(u[t].x);
            accy += v * bf2f(u[t].y);
            accz += v * bf2f(u[t].z);
            accw += v * bf2f(u[t].w);
        }
    }
    for (; j < end; j++) {
        int2 e = edges[j];
        float v = __int_as_float(e.y);
        ushortx4 u = *(const ushortx4*)(H0 + (size_t)e.x * 256 + fo);
        accx += v * bf2f(u.x);
        accy += v * bf2f(u.y);
        accz += v * bf2f(u.z);
        accw += v * bf2f(u.w);
    }
    float4 o;
    o.x = fmaxf(accx, 0.f); o.y = fmaxf(accy, 0.f);
    o.z = fmaxf(accz, 0.f); o.w = fmaxf(accw, 0.f);
    *(float4*)(H1 + (size_t)i * 256 + fo) = o;
}

// ---------------------------------------------------------------- column stats F=256
__global__ __launch_bounds__(256) void colstats1_kernel(const float* __restrict__ H1,
                                                        float* __restrict__ sums,
                                                        float* __restrict__ sumsq,
                                                        int n, int rpb) {
    int tid = threadIdx.x;
    int r0 = blockIdx.x * rpb;
    int r1 = min(r0 + rpb, n);
    float s = 0.f, q = 0.f;
    for (int rr = r0; rr < r1; rr++) {
        float v = H1[(size_t)rr * 256 + tid];
        s += v; q += v * v;
    }
    atomicAdd(&sums[tid], s);
    atomicAdd(&sumsq[tid], q);
}

__global__ void bnparams_kernel(const float* __restrict__ sums, const float* __restrict__ sumsq,
                                const float* __restrict__ gamma, const float* __restrict__ beta,
                                float* __restrict__ scale, float* __restrict__ shift,
                                int C, float invN) {
    int c = threadIdx.x;
    if (c < C) {
        float mean = sums[c] * invN;
        float var  = sumsq[c] * invN - mean * mean;
        float rstd = rsqrtf(var + EPS);
        float sc   = gamma[c] * rstd;
        scale[c] = sc;
        shift[c] = beta[c] - mean * sc;
    }
}

// ---------------------------------------------------------------- GEMM2: relu(bn1(H1)) @ W2 -> bf16
__global__ __launch_bounds__(256) void gemm2_kernel(const float* __restrict__ H1,
                                                    const float* __restrict__ W2,
                                                    const float* __restrict__ scale1,
                                                    const float* __restrict__ shift1,
                                                    unsigned short* __restrict__ H2, int M) {
    __shared__ float As[8][129];
    __shared__ float Bs[8][64];
    int tid = threadIdx.x;
    int tx = tid & 15, ty = tid >> 4;
    int rowBase = blockIdx.x * 128;
    float acc[8][4];
#pragma unroll
    for (int i = 0; i < 8; i++)
#pragma unroll
        for (int j = 0; j < 4; j++) acc[i][j] = 0.0f;

    int r   = tid >> 1;
    int kq  = (tid & 1) * 4;
    int bkk = tid >> 6;
    int bcol = tid & 63;

    for (int k0 = 0; k0 < 256; k0 += 8) {
        float4 a4 = make_float4(0.f, 0.f, 0.f, 0.f);
        int arow = rowBase + r;
        if (arow < M) a4 = *(const float4*)(H1 + (size_t)arow * 256 + k0 + kq);
        float av[4] = {a4.x, a4.y, a4.z, a4.w};
#pragma unroll
        for (int jj = 0; jj < 4; jj++) {
            int kk = k0 + kq + jj;
            float t = av[jj] * scale1[kk] + shift1[kk];
            As[kq + jj][r] = fmaxf(t, 0.0f);
        }
        Bs[bkk][bcol]     = W2[(size_t)(k0 + bkk) * 64 + bcol];
        Bs[bkk + 4][bcol] = W2[(size_t)(k0 + bkk + 4) * 64 + bcol];
        __syncthreads();
#pragma unroll
        for (int k = 0; k < 8; k++) {
            float ra[8], rb[4];
#pragma unroll
            for (int i = 0; i < 8; i++) ra[i] = As[k][ty * 8 + i];
#pragma unroll
            for (int j = 0; j < 4; j++) rb[j] = Bs[k][tx * 4 + j];
#pragma unroll
            for (int i = 0; i < 8; i++)
#pragma unroll
                for (int j = 0; j < 4; j++) acc[i][j] += ra[i] * rb[j];
        }
        __syncthreads();
    }
#pragma unroll
    for (int i = 0; i < 8; i++) {
        int crow = rowBase + ty * 8 + i;
        if (crow < M) {
            ushortx4 o;
            o.x = f2bf(acc[i][0]); o.y = f2bf(acc[i][1]);
            o.z = f2bf(acc[i][2]); o.w = f2bf(acc[i][3]);
            *(ushortx4*)(H2 + (size_t)crow * 64 + tx * 4) = o;
        }
    }
}

// ---------------------------------------------------------------- SpMM2 (F=64): half-wave per row, bf16 gather
__global__ __launch_bounds__(256) void agg2_kernel(const unsigned short* __restrict__ H2,
                                                   const int* __restrict__ rs,
                                                   const int2* __restrict__ edges,
                                                   float* __restrict__ H3, int n) {
    int w = threadIdx.x >> 6, lane = threadIdx.x & 63;
    int half = lane >> 5, sub = lane & 31;
    int i = blockIdx.x * 8 + w * 2 + half;
    if (i >= n) return;
    int start = rs[i], end = rs[i + 1];
    int fo = sub << 1;
    float accx = 0.f, accy = 0.f;
    int j = start;
    for (; j + 4 <= end; j += 4) {
        int2 e[4];
        ushortx2 u[4];
#pragma unroll
        for (int t = 0; t < 4; t++) e[t] = edges[j + t];
#pragma unroll
        for (int t = 0; t < 4; t++)
            u[t] = *(const ushortx2*)(H2 + (size_t)e[t].x * 64 + fo);
#pragma unroll
        for (int t = 0; t < 4; t++) {
            float v = __int_as_float(e[t].y);
            accx += v * bf2f(u[t].x);
            accy += v * bf2f(u[t].y);
        }
    }
    for (; j < end; j++) {
        int2 e = edges[j];
        float v = __int_as_float(e.y);
        ushortx2 u = *(const ushortx2*)(H2 + (size_t)e.x * 64 + fo);
        accx += v * bf2f(u.x);
        accy += v * bf2f(u.y);
    }
    float2 o;
    o.x = fmaxf(accx, 0.f);
    o.y = fmaxf(accy, 0.f);
    *(float2*)(H3 + (size_t)i * 64 + fo) = o;
}

// ---------------------------------------------------------------- column stats F=64
__global__ __launch_bounds__(256) void colstats2_kernel(const float* __restrict__ H3,
                                                        float* __restrict__ sums,
                                                        float* __restrict__ sumsq,
                                                        int n, int rpb) {
    int c = threadIdx.x & 63, rsub = threadIdx.x >> 6;
    int base = blockIdx.x * rpb;
    int r1 = min(base + rpb, n);
    float s = 0.f, q = 0.f;
    for (int rr = base + rsub; rr < r1; rr += 4) {
        float v = H3[(size_t)rr * 64 + c];
        s += v; q += v * v;
    }
    atomicAdd(&sums[c], s);
    atomicAdd(&sumsq[c], q);
}

__global__ void bnapply_kernel(float* __restrict__ out, const float* __restrict__ scale,
                               const float* __restrict__ shift, int total) {
    int idx = blockIdx.x * 256 + threadIdx.x;
    if (idx < total) {
        int c = idx & 63;
        out[idx] = out[idx] * scale[c] + shift[c];
    }
}

// ---------------------------------------------------------------- launch
extern "C" void kernel_launch(void* const* d_in, const int* in_sizes, int n_in,
                              void* d_out, int out_size, void* d_ws, size_t ws_size,
                              hipStream_t stream) {
    const float* x    = (const float*)d_in[0];
    const int*   erow = (const int*)d_in[1];
    const int*   ecol = (const int*)d_in[2];
    const float* ev   = (const float*)d_in[3];
    const float* W1   = (const float*)d_in[4];
    const float* g1   = (const float*)d_in[5];
    const float* b1   = (const float*)d_in[6];
    const float* W2   = (const float*)d_in[7];
    const float* g2   = (const float*)d_in[8];
    const float* b2   = (const float*)d_in[9];
    float* out = (float*)d_out;

    int n = in_sizes[0] / 512;   // 100000
    int E = in_sizes[1];         // 3200000
    int nb = (n + 127) >> 7;     // 782 buckets of 128 rows (<=1024 assumed)

    char* ws = (char*)d_ws;
    size_t off = 0;
    auto alloc = [&](size_t bytes) { size_t o = off; off += (bytes + 255) & ~(size_t)255; return o; };

    int*   hist          = (int*)(ws + alloc((size_t)nb * 4));
    int*   bucket_start  = (int*)(ws + alloc((size_t)(nb + 1) * 4));
    int*   bucket_cursor = (int*)(ws + alloc((size_t)nb * 16 * 4));
    int*   row_start     = (int*)(ws + alloc((size_t)(n + 1) * 4));
    int2*  tmp           = (int2*)(ws + alloc((size_t)E * 8));
    int2*  edges         = (int2*)(ws + alloc((size_t)E * 8));
    unsigned short* h0  = (unsigned short*)(ws + alloc((size_t)n * 256 * 2));
    float* h1           = (float*)(ws + alloc((size_t)n * 256 * 4));
    unsigned short* h2  = (unsigned short*)(ws + alloc((size_t)n * 64 * 2));
    unsigned short* w1hi = (unsigned short*)(ws + alloc((size_t)256 * 512 * 2));
    unsigned short* w1lo = (unsigned short*)(ws + alloc((size_t)256 * 512 * 2));
    float* stats        = (float*)(ws + alloc(2048 * 4));
    float* sums1  = stats;
    float* sumsq1 = stats + 256;
    float* sums2  = stats + 512;
    float* sumsq2 = stats + 576;
    float* scale1 = stats + 640;
    float* shift1 = stats + 896;
    float* scale2 = stats + 1152;
    float* shift2 = stats + 1216;

    float invN = 1.0f / (float)n;

    // 1. zero bucket histogram + stat accumulators
    zero_kernel<<<dim3((nb + 255) / 256), dim3(256), 0, stream>>>(hist, stats, nb, 640);
    // 2. LDS-aggregated bucket histogram (782 bins)
    bucket_hist_kernel<<<dim3(1024), dim3(256), 0, stream>>>(erow, hist, E, nb);
    // 3. tiny scan -> bucket_start + append cursors (+ row_start[n]=E)
    bucket_scan_kernel<<<dim3(1), dim3(1024), 0, stream>>>(hist, bucket_start, bucket_cursor, row_start, nb, n, E);
    // 4. pass 1: line-dense append into per-bucket staging regions
    bucket_scatter_kernel<<<dim3(2048), dim3(256), 0, stream>>>(erow, ecol, ev, bucket_cursor, tmp, E);
    // 5. pass 2: per-bucket LDS count+scan -> row_start + exact CSR placement
    place_kernel<<<dim3(nb), dim3(256), 0, stream>>>(tmp, bucket_start, row_start, edges, n);
    // 6. W1 -> split bf16 transposed
    prep_w1_kernel<<<dim3(512), dim3(256), 0, stream>>>(W1, w1hi, w1lo);
    // 7. h0(bf16) = x @ W1  (split-bf16 MFMA, ~fp32 accurate)
    gemm1_mfma_kernel<<<dim3(2, (n + 127) / 128), dim3(256), 0, stream>>>(x, w1hi, w1lo, h0, n);
    // 8. h1 = relu(spmm(h0))  (bf16 gather, fp32 accum; y = feature half)
    agg1_kernel<<<dim3((n + 7) / 8, 2), dim3(256), 0, stream>>>(h0, row_start, edges, h1, n);
    // 9. BN1 stats
    colstats1_kernel<<<dim3(400), dim3(256), 0, stream>>>(h1, sums1, sumsq1, n, (n + 399) / 400);
    // 10. BN1 params
    bnparams_kernel<<<dim3(1), dim3(256), 0, stream>>>(sums1, sumsq1, g1, b1, scale1, shift1, 256, invN);
    // 11. h2(bf16) = relu(bn1(h1)) @ W2  (fp32 vector ALU, exact)
    gemm2_kernel<<<dim3((n + 127) / 128), dim3(256), 0, stream>>>(h1, W2, scale1, shift1, h2, n);
    // 12. out_pre = relu(spmm(h2))  (bf16 gather, written into d_out)
    agg2_kernel<<<dim3((n + 7) / 8), dim3(256), 0, stream>>>(h2, row_start, edges, out, n);
    // 13. BN2 stats
    colstats2_kernel<<<dim3(200), dim3(256), 0, stream>>>(out, sums2, sumsq2, n, (n + 199) / 200);
    // 14. BN2 params
    bnparams_kernel<<<dim3(1), dim3(64), 0, stream>>>(sums2, sumsq2, g2, b2, scale2, shift2, 64, invN);
    // 15. in-place BN apply on d_out
    bnapply_kernel<<<dim3((n * 64 + 255) / 256), dim3(256), 0, stream>>>(out, scale2, shift2, n * 64);

    (void)n_in; (void)out_size; (void)ws_size;
}

// Round 6
// 1091.704 us; speedup vs baseline: 1.3503x; 1.0121x over previous
//
#include <hip/hip_runtime.h>

#define EPS 1e-5f

typedef __attribute__((ext_vector_type(8))) short short8;
typedef __attribute__((ext_vector_type(4))) float floatx4;
typedef __attribute__((ext_vector_type(4))) unsigned short ushortx4;
typedef __attribute__((ext_vector_type(2))) unsigned short ushortx2;

__device__ __forceinline__ unsigned short f2bf(float f) {
    unsigned u = __float_as_uint(f);
    unsigned r = (u + 0x7FFFu + ((u >> 16) & 1u)) >> 16;
    return (unsigned short)r;
}
__device__ __forceinline__ float bf2f(unsigned short h) {
    return __uint_as_float((unsigned)h << 16);
}

// ---------------------------------------------------------------- utilities
// zero bucket histogram (782 ints) + stat accumulators; single small grid
__global__ void zero_kernel(int* __restrict__ hist, float* __restrict__ stats,
                            int nb, int n_stats) {
    int i = blockIdx.x * 256 + threadIdx.x;
    if (i < nb)      hist[i] = 0;
    if (i < n_stats) stats[i] = 0.0f;
}

// LDS-aggregated histogram of buckets (row>>7): 782 bins, near-free vs
// per-row global atomics.
__global__ __launch_bounds__(256) void bucket_hist_kernel(const int* __restrict__ erow,
                                                          int* __restrict__ hist,
                                                          int E, int nb) {
    __shared__ int cnt[1024];
    for (int i = threadIdx.x; i < nb; i += 256) cnt[i] = 0;
    __syncthreads();
    int stride = gridDim.x * 256;
    for (int j = blockIdx.x * 256 + threadIdx.x; j < E; j += stride)
        atomicAdd(&cnt[erow[j] >> 7], 1);
    __syncthreads();
    for (int i = threadIdx.x; i < nb; i += 256) {
        int c = cnt[i];
        if (c) atomicAdd(&hist[i], c);
    }
}

// single-block exclusive scan over hist[nb] (nb=782 <= 1024) ->
// bucket_start[nb+1] + padded append cursors. Single source of truth.
__global__ __launch_bounds__(1024) void bucket_scan_kernel(const int* __restrict__ hist,
                                                           int* __restrict__ bucket_start,
                                                           int* __restrict__ bucket_cursor,
                                                           int* __restrict__ row_start,
                                                           int nb, int n, int E) {
    __shared__ int lds[1024];
    int t = threadIdx.x;
    int v = (t < nb) ? hist[t] : 0;
    lds[t] = v;
    __syncthreads();
    for (int off = 1; off < 1024; off <<= 1) {
        int w = (t >= off) ? lds[t - off] : 0;
        __syncthreads();
        lds[t] += w;
        __syncthreads();
    }
    int ex = lds[t] - v;  // exclusive prefix
    if (t < nb) {
        bucket_start[t] = ex;
        bucket_cursor[t * 16] = ex;   // one cursor per 64B line
    }
    if (t == 0) { bucket_start[nb] = E; row_start[n] = E; }
}

// pass 1: append edges into their bucket's region of the staging array.
// Appends per bucket are temporally dense -> ~1x write amplification.
// key packs localrow (7b) above col (17b). Overflow impossible by construction.
__global__ __launch_bounds__(256) void bucket_scatter_kernel(const int* __restrict__ erow,
                                                             const int* __restrict__ ecol,
                                                             const float* __restrict__ ev,
                                                             int* __restrict__ bucket_cursor,
                                                             int2* __restrict__ tmp, int E) {
    int stride = gridDim.x * 256;
    for (int j = blockIdx.x * 256 + threadIdx.x; j < E; j += stride) {
        int r = erow[j];
        int b = r >> 7, lr = r & 127;
        int p = atomicAdd(&bucket_cursor[b * 16], 1);
        tmp[p] = make_int2(ecol[j] | (lr << 17), __float_as_int(ev[j]));
    }
}

// pass 2: one block per bucket. Derives per-row offsets ITSELF via LDS
// count+scan of its own region, writes row_start[128 rows] and places edges
// exactly. Region is ~32KB, L2-hot for the second read.
__global__ __launch_bounds__(256) void place_kernel(const int2* __restrict__ tmp,
                                                    const int* __restrict__ bucket_start,
                                                    int* __restrict__ row_start,
                                                    int2* __restrict__ edges, int n) {
    __shared__ int cnt[128], scn[128], cur[128];
    int b = blockIdx.x, t = threadIdx.x;
    int bstart = bucket_start[b], bend = bucket_start[b + 1];
    if (t < 128) cnt[t] = 0;
    __syncthreads();
    for (int j = bstart + t; j < bend; j += 256)
        atomicAdd(&cnt[((unsigned)tmp[j].x) >> 17], 1);
    __syncthreads();
    if (t < 128) scn[t] = cnt[t];
    __syncthreads();
#pragma unroll
    for (int off = 1; off < 128; off <<= 1) {
        int v = 0;
        if (t < 128 && t >= off) v = scn[t - off];
        __syncthreads();
        if (t < 128) scn[t] += v;
        __syncthreads();
    }
    if (t < 128) {
        int pref = bstart + scn[t] - cnt[t];   // exclusive prefix within bucket
        cur[t] = pref;
        int r = b * 128 + t;
        if (r < n) row_start[r] = pref;
    }
    __syncthreads();
    for (int j = bstart + t; j < bend; j += 256) {
        int2 e = tmp[j];
        int lr = ((unsigned)e.x) >> 17;
        int pos = atomicAdd(&cur[lr], 1);
        edges[pos] = make_int2(e.x & 0x1FFFF, e.y);
    }
}

// ---------------------------------------------------------------- W1 -> split bf16 transposed [256][512]
__global__ void prep_w1_kernel(const float* __restrict__ W1,
                               unsigned short* __restrict__ Bhi,
                               unsigned short* __restrict__ Blo) {
    int idx = blockIdx.x * 256 + threadIdx.x;   // 131072 total
    int nn = idx >> 9, k = idx & 511;
    float w = W1[(size_t)k * 256 + nn];
    unsigned short hi = f2bf(w);
    float rem = w - bf2f(hi);
    Bhi[idx] = hi;
    Blo[idx] = f2bf(rem);
}

// ---------------------------------------------------------------- GEMM1 (split-bf16 MFMA, ~fp32 exact):
// h0[M,256](bf16) = A[M,512](fp32) @ W1.  acc += ah*bh + al*bh + ah*bl.
// BN=256 (full width): each A-tile fetched+converted exactly ONCE (was 2x).
// 512 threads / 8 waves: wm in {0,1} (rows), wn in {0..3} (cols).
__global__ __launch_bounds__(512) void gemm1_mfma_kernel(const float* __restrict__ A,
                                                         const unsigned short* __restrict__ Bhi,
                                                         const unsigned short* __restrict__ Blo,
                                                         unsigned short* __restrict__ H0, int M) {
    __shared__ unsigned short AsH[128][32];
    __shared__ unsigned short AsL[128][32];
    __shared__ unsigned short BsH[256][32];
    __shared__ unsigned short BsL[256][32];
    int tid  = threadIdx.x;
    int lane = tid & 63, w = tid >> 6;
    int wm = w & 1, wn = w >> 1;
    int rowBase = blockIdx.x * 128;

    floatx4 acc[4][4];
#pragma unroll
    for (int i = 0; i < 4; i++)
#pragma unroll
        for (int j = 0; j < 4; j++)
#pragma unroll
            for (int r = 0; r < 4; r++) acc[i][j][r] = 0.0f;

    // A staging: 128 rows x 32 k-cols, 512 threads -> 8 floats each
    int ar = tid >> 2;
    int aq = (tid & 3) * 8;
    bool aval = (rowBase + ar) < M;
    const float* aptr = A + (size_t)(rowBase + ar) * 512 + aq;

    // B staging: 256 out-cols x 32 k-cols, 512 threads -> 16 shorts each
    int br  = tid >> 1;
    int bq  = (tid & 1) * 16;
    const unsigned short* bhptr = Bhi + (size_t)br * 512 + bq;
    const unsigned short* blptr = Blo + (size_t)br * 512 + bq;

    int cl = lane & 15, quad = lane >> 4;
    int q8 = quad * 8;

    for (int k0 = 0; k0 < 512; k0 += 32) {
        float f[8];
        if (aval) {
            *(float4*)&f[0] = *(const float4*)(aptr + k0);
            *(float4*)&f[4] = *(const float4*)(aptr + k0 + 4);
        } else {
#pragma unroll
            for (int t = 0; t < 8; t++) f[t] = 0.0f;
        }
        union { unsigned short s[8]; uint4 q; } ph, pl;
#pragma unroll
        for (int t = 0; t < 8; t++) {
            unsigned short hi = f2bf(f[t]);
            ph.s[t] = hi;
            pl.s[t] = f2bf(f[t] - bf2f(hi));
        }
        *(uint4*)&AsH[ar][aq] = ph.q;
        *(uint4*)&AsL[ar][aq] = pl.q;
        *(uint4*)&BsH[br][bq]     = *(const uint4*)(bhptr + k0);
        *(uint4*)&BsH[br][bq + 8] = *(const uint4*)(bhptr + k0 + 8);
        *(uint4*)&BsL[br][bq]     = *(const uint4*)(blptr + k0);
        *(uint4*)&BsL[br][bq + 8] = *(const uint4*)(blptr + k0 + 8);
        __syncthreads();

        short8 ah[4], al[4], bh[4], bl[4];
#pragma unroll
        for (int mt = 0; mt < 4; mt++) {
            ah[mt] = *(short8*)&AsH[wm * 64 + mt * 16 + cl][q8];
            al[mt] = *(short8*)&AsL[wm * 64 + mt * 16 + cl][q8];
        }
#pragma unroll
        for (int nt = 0; nt < 4; nt++) {
            bh[nt] = *(short8*)&BsH[wn * 64 + nt * 16 + cl][q8];
            bl[nt] = *(short8*)&BsL[wn * 64 + nt * 16 + cl][q8];
        }
#pragma unroll
        for (int mt = 0; mt < 4; mt++)
#pragma unroll
            for (int nt = 0; nt < 4; nt++) {
                acc[mt][nt] = __builtin_amdgcn_mfma_f32_16x16x32_bf16(ah[mt], bh[nt], acc[mt][nt], 0, 0, 0);
                acc[mt][nt] = __builtin_amdgcn_mfma_f32_16x16x32_bf16(al[mt], bh[nt], acc[mt][nt], 0, 0, 0);
                acc[mt][nt] = __builtin_amdgcn_mfma_f32_16x16x32_bf16(ah[mt], bl[nt], acc[mt][nt], 0, 0, 0);
            }
        __syncthreads();
    }

#pragma unroll
    for (int mt = 0; mt < 4; mt++) {
#pragma unroll
        for (int reg = 0; reg < 4; reg++) {
            int gr = rowBase + wm * 64 + mt * 16 + quad * 4 + reg;
            if (gr < M) {
#pragma unroll
                for (int nt = 0; nt < 4; nt++) {
                    H0[(size_t)gr * 256 + wn * 64 + nt * 16 + cl] = f2bf(acc[mt][nt][reg]);
                }
            }
        }
    }
}

// ---------------------------------------------------------------- SpMM1 (F=256, split into 2 half-F passes):
// gridDim.y = 2 halves of the feature dim (soft-sequenced by dispatch order);
// 32-lane group per row-half, 8 B/lane gathers.
__global__ __launch_bounds__(256) void agg1_kernel(const unsigned short* __restrict__ H0,
                                                   const int* __restrict__ rs,
                                                   const int2* __restrict__ edges,
                                                   float* __restrict__ H1, int n) {
    int g = threadIdx.x >> 5, sub = threadIdx.x & 31;
    int i = blockIdx.x * 8 + g;
    if (i >= n) return;
    int start = rs[i], end = rs[i + 1];
    int fo = blockIdx.y * 128 + (sub << 2);
    float accx = 0.f, accy = 0.f, accz = 0.f, accw = 0.f;
    int j = start;
    for (; j + 8 <= end; j += 8) {
        int2 e[8];
        ushortx4 u[8];
#pragma unroll
        for (int t = 0; t < 8; t++) e[t] = edges[j + t];
#pragma unroll
        for (int t = 0; t < 8; t++)
            u[t] = *(const ushortx4*)(H0 + (size_t)e[t].x * 256 + fo);
#pragma unroll
        for (int t = 0; t < 8; t++) {
            float v = __int_as_float(e[t].y);
            accx += v * bf2f(u[t].x);
            accy += v * bf2f(u[t].y);
            accz += v * bf2f(u[t].z);
            accw += v * bf2f(u[t].w);
        }
    }
    for (; j < end; j++) {
        int2 e = edges[j];
        float v = __int_as_float(e.y);
        ushortx4 u = *(const ushortx4*)(H0 + (size_t)e.x * 256 + fo);
        accx += v * bf2f(u.x);
        accy += v * bf2f(u.y);
        accz += v * bf2f(u.z);
        accw += v * bf2f(u.w);
    }
    float4 o;
    o.x = fmaxf(accx, 0.f); o.y = fmaxf(accy, 0.f);
    o.z = fmaxf(accz, 0.f); o.w = fmaxf(accw, 0.f);
    *(float4*)(H1 + (size_t)i * 256 + fo) = o;
}

// ---------------------------------------------------------------- column stats F=256
__global__ __launch_bounds__(256) void colstats1_kernel(const float* __restrict__ H1,
                                                        float* __restrict__ sums,
                                                        float* __restrict__ sumsq,
                                                        int n, int rpb) {
    int tid = threadIdx.x;
    int r0 = blockIdx.x * rpb;
    int r1 = min(r0 + rpb, n);
    float s = 0.f, q = 0.f;
    for (int rr = r0; rr < r1; rr++) {
        float v = H1[(size_t)rr * 256 + tid];
        s += v; q += v * v;
    }
    atomicAdd(&sums[tid], s);
    atomicAdd(&sumsq[tid], q);
}

__global__ void bnparams_kernel(const float* __restrict__ sums, const float* __restrict__ sumsq,
                                const float* __restrict__ gamma, const float* __restrict__ beta,
                                float* __restrict__ scale, float* __restrict__ shift,
                                int C, float invN) {
    int c = threadIdx.x;
    if (c < C) {
        float mean = sums[c] * invN;
        float var  = sumsq[c] * invN - mean * mean;
        float rstd = rsqrtf(var + EPS);
        float sc   = gamma[c] * rstd;
        scale[c] = sc;
        shift[c] = beta[c] - mean * sc;
    }
}

// ---------------------------------------------------------------- GEMM2: relu(bn1(H1)) @ W2 -> bf16
__global__ __launch_bounds__(256) void gemm2_kernel(const float* __restrict__ H1,
                                                    const float* __restrict__ W2,
                                                    const float* __restrict__ scale1,
                                                    const float* __restrict__ shift1,
                                                    unsigned short* __restrict__ H2, int M) {
    __shared__ float As[8][129];
    __shared__ float Bs[8][64];
    int tid = threadIdx.x;
    int tx = tid & 15, ty = tid >> 4;
    int rowBase = blockIdx.x * 128;
    float acc[8][4];
#pragma unroll
    for (int i = 0; i < 8; i++)
#pragma unroll
        for (int j = 0; j < 4; j++) acc[i][j] = 0.0f;

    int r   = tid >> 1;
    int kq  = (tid & 1) * 4;
    int bkk = tid >> 6;
    int bcol = tid & 63;

    for (int k0 = 0; k0 < 256; k0 += 8) {
        float4 a4 = make_float4(0.f, 0.f, 0.f, 0.f);
        int arow = rowBase + r;
        if (arow < M) a4 = *(const float4*)(H1 + (size_t)arow * 256 + k0 + kq);
        float av[4] = {a4.x, a4.y, a4.z, a4.w};
#pragma unroll
        for (int jj = 0; jj < 4; jj++) {
            int kk = k0 + kq + jj;
            float t = av[jj] * scale1[kk] + shift1[kk];
            As[kq + jj][r] = fmaxf(t, 0.0f);
        }
        Bs[bkk][bcol]     = W2[(size_t)(k0 + bkk) * 64 + bcol];
        Bs[bkk + 4][bcol] = W2[(size_t)(k0 + bkk + 4) * 64 + bcol];
        __syncthreads();
#pragma unroll
        for (int k = 0; k < 8; k++) {
            float ra[8], rb[4];
#pragma unroll
            for (int i = 0; i < 8; i++) ra[i] = As[k][ty * 8 + i];
#pragma unroll
            for (int j = 0; j < 4; j++) rb[j] = Bs[k][tx * 4 + j];
#pragma unroll
            for (int i = 0; i < 8; i++)
#pragma unroll
                for (int j = 0; j < 4; j++) acc[i][j] += ra[i] * rb[j];
        }
        __syncthreads();
    }
#pragma unroll
    for (int i = 0; i < 8; i++) {
        int crow = rowBase + ty * 8 + i;
        if (crow < M) {
            ushortx4 o;
            o.x = f2bf(acc[i][0]); o.y = f2bf(acc[i][1]);
            o.z = f2bf(acc[i][2]); o.w = f2bf(acc[i][3]);
            *(ushortx4*)(H2 + (size_t)crow * 64 + tx * 4) = o;
        }
    }
}

// ---------------------------------------------------------------- SpMM2 (F=64): half-wave per row, bf16 gather
__global__ __launch_bounds__(256) void agg2_kernel(const unsigned short* __restrict__ H2,
                                                   const int* __restrict__ rs,
                                                   const int2* __restrict__ edges,
                                                   float* __restrict__ H3, int n) {
    int w = threadIdx.x >> 6, lane = threadIdx.x & 63;
    int half = lane >> 5, sub = lane & 31;
    int i = blockIdx.x * 8 + w * 2 + half;
    if (i >= n) return;
    int start = rs[i], end = rs[i + 1];
    int fo = sub << 1;
    float accx = 0.f, accy = 0.f;
    int j = start;
    for (; j + 4 <= end; j += 4) {
        int2 e[4];
        ushortx2 u[4];
#pragma unroll
        for (int t = 0; t < 4; t++) e[t] = edges[j + t];
#pragma unroll
        for (int t = 0; t < 4; t++)
            u[t] = *(const ushortx2*)(H2 + (size_t)e[t].x * 64 + fo);
#pragma unroll
        for (int t = 0; t < 4; t++) {
            float v = __int_as_float(e[t].y);
            accx += v * bf2f(u[t].x);
            accy += v * bf2f(u[t].y);
        }
    }
    for (; j < end; j++) {
        int2 e = edges[j];
        float v = __int_as_float(e.y);
        ushortx2 u = *(const ushortx2*)(H2 + (size_t)e.x * 64 + fo);
        accx += v * bf2f(u.x);
        accy += v * bf2f(u.y);
    }
    float2 o;
    o.x = fmaxf(accx, 0.f);
    o.y = fmaxf(accy, 0.f);
    *(float2*)(H3 + (size_t)i * 64 + fo) = o;
}

// ---------------------------------------------------------------- column stats F=64
__global__ __launch_bounds__(256) void colstats2_kernel(const float* __restrict__ H3,
                                                        float* __restrict__ sums,
                                                        float* __restrict__ sumsq,
                                                        int n, int rpb) {
    int c = threadIdx.x & 63, rsub = threadIdx.x >> 6;
    int base = blockIdx.x * rpb;
    int r1 = min(base + rpb, n);
    float s = 0.f, q = 0.f;
    for (int rr = base + rsub; rr < r1; rr += 4) {
        float v = H3[(size_t)rr * 64 + c];
        s += v; q += v * v;
    }
    atomicAdd(&sums[c], s);
    atomicAdd(&sumsq[c], q);
}

__global__ void bnapply_kernel(float* __restrict__ out, const float* __restrict__ scale,
                               const float* __restrict__ shift, int total) {
    int idx = blockIdx.x * 256 + threadIdx.x;
    if (idx < total) {
        int c = idx & 63;
        out[idx] = out[idx] * scale[c] + shift[c];
    }
}

// ---------------------------------------------------------------- launch
extern "C" void kernel_launch(void* const* d_in, const int* in_sizes, int n_in,
                              void* d_out, int out_size, void* d_ws, size_t ws_size,
                              hipStream_t stream) {
    const float* x    = (const float*)d_in[0];
    const int*   erow = (const int*)d_in[1];
    const int*   ecol = (const int*)d_in[2];
    const float* ev   = (const float*)d_in[3];
    const float* W1   = (const float*)d_in[4];
    const float* g1   = (const float*)d_in[5];
    const float* b1   = (const float*)d_in[6];
    const float* W2   = (const float*)d_in[7];
    const float* g2   = (const float*)d_in[8];
    const float* b2   = (const float*)d_in[9];
    float* out = (float*)d_out;

    int n = in_sizes[0] / 512;   // 100000
    int E = in_sizes[1];         // 3200000
    int nb = (n + 127) >> 7;     // 782 buckets of 128 rows (<=1024 assumed)

    char* ws = (char*)d_ws;
    size_t off = 0;
    auto alloc = [&](size_t bytes) { size_t o = off; off += (bytes + 255) & ~(size_t)255; return o; };

    int*   hist          = (int*)(ws + alloc((size_t)nb * 4));
    int*   bucket_start  = (int*)(ws + alloc((size_t)(nb + 1) * 4));
    int*   bucket_cursor = (int*)(ws + alloc((size_t)nb * 16 * 4));
    int*   row_start     = (int*)(ws + alloc((size_t)(n + 1) * 4));
    int2*  tmp           = (int2*)(ws + alloc((size_t)E * 8));
    int2*  edges         = (int2*)(ws + alloc((size_t)E * 8));
    unsigned short* h0  = (unsigned short*)(ws + alloc((size_t)n * 256 * 2));
    float* h1           = (float*)(ws + alloc((size_t)n * 256 * 4));
    unsigned short* h2  = (unsigned short*)(ws + alloc((size_t)n * 64 * 2));
    unsigned short* w1hi = (unsigned short*)(ws + alloc((size_t)256 * 512 * 2));
    unsigned short* w1lo = (unsigned short*)(ws + alloc((size_t)256 * 512 * 2));
    float* stats        = (float*)(ws + alloc(2048 * 4));
    float* sums1  = stats;
    float* sumsq1 = stats + 256;
    float* sums2  = stats + 512;
    float* sumsq2 = stats + 576;
    float* scale1 = stats + 640;
    float* shift1 = stats + 896;
    float* scale2 = stats + 1152;
    float* shift2 = stats + 1216;

    float invN = 1.0f / (float)n;

    // 1. zero bucket histogram + stat accumulators
    zero_kernel<<<dim3((nb + 255) / 256), dim3(256), 0, stream>>>(hist, stats, nb, 640);
    // 2. LDS-aggregated bucket histogram (782 bins)
    bucket_hist_kernel<<<dim3(1024), dim3(256), 0, stream>>>(erow, hist, E, nb);
    // 3. tiny scan -> bucket_start + append cursors (+ row_start[n]=E)
    bucket_scan_kernel<<<dim3(1), dim3(1024), 0, stream>>>(hist, bucket_start, bucket_cursor, row_start, nb, n, E);
    // 4. pass 1: line-dense append into per-bucket staging regions
    bucket_scatter_kernel<<<dim3(2048), dim3(256), 0, stream>>>(erow, ecol, ev, bucket_cursor, tmp, E);
    // 5. pass 2: per-bucket LDS count+scan -> row_start + exact CSR placement
    place_kernel<<<dim3(nb), dim3(256), 0, stream>>>(tmp, bucket_start, row_start, edges, n);
    // 6. W1 -> split bf16 transposed
    prep_w1_kernel<<<dim3(512), dim3(256), 0, stream>>>(W1, w1hi, w1lo);
    // 7. h0(bf16) = x @ W1  (split-bf16 MFMA, BN=256: A converted once)
    gemm1_mfma_kernel<<<dim3((n + 127) / 128), dim3(512), 0, stream>>>(x, w1hi, w1lo, h0, n);
    // 8. h1 = relu(spmm(h0))  (bf16 gather, fp32 accum; y = feature half)
    agg1_kernel<<<dim3((n + 7) / 8, 2), dim3(256), 0, stream>>>(h0, row_start, edges, h1, n);
    // 9. BN1 stats
    colstats1_kernel<<<dim3(400), dim3(256), 0, stream>>>(h1, sums1, sumsq1, n, (n + 399) / 400);
    // 10. BN1 params
    bnparams_kernel<<<dim3(1), dim3(256), 0, stream>>>(sums1, sumsq1, g1, b1, scale1, shift1, 256, invN);
    // 11. h2(bf16) = relu(bn1(h1)) @ W2  (fp32 vector ALU, exact)
    gemm2_kernel<<<dim3((n + 127) / 128), dim3(256), 0, stream>>>(h1, W2, scale1, shift1, h2, n);
    // 12. out_pre = relu(spmm(h2))  (bf16 gather, written into d_out)
    agg2_kernel<<<dim3((n + 7) / 8), dim3(256), 0, stream>>>(h2, row_start, edges, out, n);
    // 13. BN2 stats
    colstats2_kernel<<<dim3(200), dim3(256), 0, stream>>>(out, sums2, sumsq2, n, (n + 199) / 200);
    // 14. BN2 params
    bnparams_kernel<<<dim3(1), dim3(64), 0, stream>>>(sums2, sumsq2, g2, b2, scale2, shift2, 64, invN);
    // 15. in-place BN apply on d_out
    bnapply_kernel<<<dim3((n * 64 + 255) / 256), dim3(256), 0, stream>>>(out, scale2, shift2, n * 64);

    (void)n_in; (void)out_size; (void)ws_size;
}